// Round 3
// 1002.780 us; speedup vs baseline: 1.0125x; 1.0125x over previous
//
#include <hip/hip_runtime.h>
#include <stdint.h>

typedef unsigned short u16;
typedef __attribute__((ext_vector_type(8))) short bf16x8;
typedef __attribute__((ext_vector_type(4))) float f32x4;

#define SEQ    2048
#define NB     2
#define NHEAD  16
#define DHEAD  128
#define DMODEL 2048
#define DFFN   8192
#define MROWS  4096   // NB*SEQ

__device__ __forceinline__ u16 f2bf(float x) {
  union { float f; uint32_t u; } v; v.f = x;
  return (u16)((v.u + 0x7fffu + ((v.u >> 16) & 1u)) >> 16);
}
__device__ __forceinline__ float bf2f(u16 h) {
  union { uint32_t u; float f; } v; v.u = ((uint32_t)h) << 16;
  return v.f;
}
__device__ __forceinline__ void gload16(const void* g, void* l) {
  __builtin_amdgcn_global_load_lds((const __attribute__((address_space(1))) void*)g,
                                   (__attribute__((address_space(3))) void*)l,
                                   16, 0, 0);
}
__device__ __forceinline__ float blockSum256(float v) {
  __shared__ float red[4];
  #pragma unroll
  for (int m = 1; m < 64; m <<= 1) v += __shfl_xor(v, m, 64);
  int w = threadIdx.x >> 6;
  if ((threadIdx.x & 63) == 0) red[w] = v;
  __syncthreads();
  float s = red[0] + red[1] + red[2] + red[3];
  __syncthreads();
  return s;
}

// ---------------- weight transpose fp32 (R,C) -> bf16 (C,R) ----------------
__global__ void transpose_w(const float* __restrict__ in, u16* __restrict__ out, int R, int C) {
  __shared__ float tile[32][33];
  int c0 = blockIdx.x * 32, r0 = blockIdx.y * 32;
  int tx = threadIdx.x, ty = threadIdx.y;
  #pragma unroll
  for (int i = 0; i < 4; ++i)
    tile[ty + 8*i][tx] = in[(size_t)(r0 + ty + 8*i) * C + c0 + tx];
  __syncthreads();
  #pragma unroll
  for (int i = 0; i < 4; ++i)
    out[(size_t)(c0 + ty + 8*i) * R + r0 + tx] = f2bf(tile[tx][ty + 8*i]);
}

// ---- ln_first: x(B,S,2049) -> v1 = log_map(x) fp32, t1 = scale*v1/rms bf16 ----
__global__ void ln_first(const float* __restrict__ x, const float* __restrict__ scale,
                         float* __restrict__ v1, u16* __restrict__ t1) {
  int row = blockIdx.x;
  const float* xr = x + (size_t)row * (DMODEL + 1) + 1;
  float vals[8]; float ss = 0.f;
  #pragma unroll
  for (int i = 0; i < 8; ++i) {
    int idx = threadIdx.x + 256 * i;
    vals[i] = xr[idx];
    ss += vals[i] * vals[i];
  }
  ss = blockSum256(ss);
  float n = sqrtf(ss);
  float f = (n < 1e-6f) ? (1.0f - n * n * (1.0f/6.0f)) : (asinhf(n) / n);
  float rms = sqrtf(f * f * ss * (1.0f / DMODEL) + 1e-6f);
  float ir = 1.0f / rms;
  #pragma unroll
  for (int i = 0; i < 8; ++i) {
    int idx = threadIdx.x + 256 * i;
    float v = f * vals[i];
    v1[(size_t)row * DMODEL + idx] = v;
    t1[(size_t)row * DMODEL + idx] = f2bf(scale[idx] * v * ir);
  }
}

// ---- rms_mid: t = scale*u/rms(u) ----
__global__ void rms_mid(const float* __restrict__ u, const float* __restrict__ scale,
                        u16* __restrict__ t) {
  int row = blockIdx.x;
  const float* ur = u + (size_t)row * DMODEL;
  float vals[8]; float ss = 0.f;
  #pragma unroll
  for (int i = 0; i < 8; ++i) { int idx = threadIdx.x + 256*i; vals[i] = ur[idx]; ss += vals[i]*vals[i]; }
  ss = blockSum256(ss);
  float ir = 1.0f / sqrtf(ss * (1.0f / DMODEL) + 1e-6f);
  #pragma unroll
  for (int i = 0; i < 8; ++i) {
    int idx = threadIdx.x + 256*i;
    t[(size_t)row*DMODEL + idx] = f2bf(scale[idx]*vals[i]*ir);
  }
}

// ---- final: out = exp_map_stable(u), row length 2049 ----
__global__ void final_exp(const float* __restrict__ u, float* __restrict__ out) {
  int row = blockIdx.x;
  const float* ur = u + (size_t)row * DMODEL;
  float vals[8]; float ss = 0.f;
  #pragma unroll
  for (int i = 0; i < 8; ++i) { int idx = threadIdx.x + 256*i; vals[i] = ur[idx]; ss += vals[i]*vals[i]; }
  ss = blockSum256(ss);
  float n = sqrtf(ss);
  float f = (n < 1e-6f) ? (1.0f + n*n*(1.0f/6.0f)) : (sinhf(n)/n);
  float* orow = out + (size_t)row * (DMODEL + 1);
  if (threadIdx.x == 0) orow[0] = sqrtf(1.0f + f*f*ss);
  #pragma unroll
  for (int i = 0; i < 8; ++i) { int idx = threadIdx.x + 256*i; orow[1+idx] = f*vals[i]; }
}

// ============================================================================
// GEMM 256x256 tile, BK=64, 8 waves (2M x 4N), 8-phase counted-vmcnt schedule
// (T3+T4), st_16x32 LDS swizzle (T2), setprio around MFMA (T5), XCD swizzle (T1).
// LDS: STATIC 131072 B = 2 buffers x (A 256x64 + B 256x64) bf16.
// Per buffer: A half h at +h*16384, B at +32768 + h*16384.
// Within a 128x64 half: subtile si=(row>>4)*2+(col>>5) of 16x32 elems, 1024 B
// contiguous; swizzle: byte ^= ((byte>>9)&1)<<5.
// Staging writes LINEAR LDS via global_load_lds; the per-lane GLOBAL source is
// inverse-swizzled (rule 21: both-sides-or-neither).
// Schedule per K-tile t (buf = t&1), quadrant order (0,0),(1,0),(1,1),(0,1):
//   p0: read a0,b0 | stage B-h0(t+1,buf^1) | bar | 16 MFMA | bar
//   p1: read a1    | stage B-h1(t+1,buf^1) | bar | 16 MFMA | bar
//   p2: read b1    | stage A-h0(t+2,buf)   | bar | 16 MFMA | bar
//   p3:            | stage A-h1(t+2,buf)   | bar | 16 MFMA | vmcnt(4) | bar
// Safety: stages into buf (t+2's A) issue only after p1's closing barrier, by
// which point every wave's A reads (p0/p1 ds_reads, drained by lgkmcnt before
// their MFMAs) completed. vmcnt(4) leaves exactly the p2/p3 stages in flight.
// ============================================================================
template<int EPI>
__global__ __launch_bounds__(512, 2) void gemm256(
    const u16* __restrict__ A, const u16* __restrict__ Bt,
    u16* __restrict__ Cb, float* Cf, const float* add,
    int M, int N, int K)
{
  __shared__ __attribute__((aligned(128))) char smem[131072];
  const int tid = threadIdx.x;
  const int w = tid >> 6, lane = tid & 63;
  const int lrow = lane & 15, kq = lane >> 4;
  const int wm = w >> 2, wn = w & 3;

  // T1: XCD-aware bijective swizzle (all grids are multiples of 8)
  const int nwg = gridDim.x;
  const int cpx = nwg >> 3;
  const int sid = (blockIdx.x & 7) * cpx + (blockIdx.x >> 3);
  const int NX = N >> 8;
  const int bx = sid % NX, by = sid / NX;
  const int m0 = by * 256, n0 = bx * 256;
  const int NT = K >> 6;          // K-tiles

  // inverse-swizzled global source offsets for the 2 staging rounds
  size_t goff[2];
  #pragma unroll
  for (int r = 0; r < 2; ++r) {
    int L = r * 8192 + tid * 16;                  // linear LDS byte this thread fills
    int U = L ^ (((L >> 9) & 1) << 5);            // unswizzled byte offset in half
    int si = U >> 10;
    int row = (si >> 1) * 16 + ((U >> 6) & 15);
    int col = (si & 1) * 32 + ((U & 63) >> 1);
    goff[r] = (size_t)row * K + col;
  }
  auto stage_half = [&](const u16* g, int ldsOff) {
    #pragma unroll
    for (int r = 0; r < 2; ++r)
      gload16(g + goff[r], smem + ldsOff + r * 8192 + w * 1024);
  };

  const u16* A0 = A  + (size_t)m0 * K;
  const u16* A1 = A  + (size_t)(m0 + 128) * K;
  const u16* B0 = Bt + (size_t)n0 * K;
  const u16* B1 = Bt + (size_t)(n0 + 128) * K;

  // swizzled per-lane fragment byte offset within a half
  const int aoff = (lrow * 64 + kq * 16) ^ ((lrow & 8) << 2);

  f32x4 acc[8][4] = {};

  // ---- prologue: tile0 (4 halves) + tile1 A halves; wait tile0 resident ----
  stage_half(A0, 0);
  stage_half(A1, 16384);
  stage_half(B0, 32768);
  stage_half(B1, 49152);
  stage_half(A0 + 64, 65536);
  stage_half(A1 + 64, 65536 + 16384);
  asm volatile("s_waitcnt vmcnt(4)" ::: "memory");
  asm volatile("s_barrier" ::: "memory");

  for (int t = 0; t < NT; ++t) {
    const int buf = t & 1;
    const char* ab = smem + buf * 65536 + wm * 16384 + aoff;
    const char* bb = smem + buf * 65536 + 32768 + (wn >> 1) * 16384 + (wn & 1) * 8192 + aoff;
    bf16x8 a0[4][2], a1[4][2], b0[2][2], b1[2][2];

    // ================= phase 0: quad (0,0) =================
    #pragma unroll
    for (int i = 0; i < 4; ++i)
      #pragma unroll
      for (int kk = 0; kk < 2; ++kk)
        a0[i][kk] = *(const bf16x8*)(ab + (i*2 + kk) * 1024);
    #pragma unroll
    for (int j = 0; j < 2; ++j)
      #pragma unroll
      for (int kk = 0; kk < 2; ++kk)
        b0[j][kk] = *(const bf16x8*)(bb + (j*2 + kk) * 1024);
    if (t + 1 < NT) stage_half(B0 + (t+1)*64, (buf^1)*65536 + 32768);
    asm volatile("s_barrier" ::: "memory");
    __builtin_amdgcn_s_setprio(1);
    #pragma unroll
    for (int kk = 0; kk < 2; ++kk)
      #pragma unroll
      for (int i = 0; i < 4; ++i)
        #pragma unroll
        for (int j = 0; j < 2; ++j)
          acc[i][j] = __builtin_amdgcn_mfma_f32_16x16x32_bf16(a0[i][kk], b0[j][kk], acc[i][j], 0, 0, 0);
    __builtin_amdgcn_s_setprio(0);
    asm volatile("s_barrier" ::: "memory");

    // ================= phase 1: quad (1,0) =================
    #pragma unroll
    for (int i = 0; i < 4; ++i)
      #pragma unroll
      for (int kk = 0; kk < 2; ++kk)
        a1[i][kk] = *(const bf16x8*)(ab + ((4 + i)*2 + kk) * 1024);
    if (t + 1 < NT) stage_half(B1 + (t+1)*64, (buf^1)*65536 + 49152);
    asm volatile("s_barrier" ::: "memory");
    __builtin_amdgcn_s_setprio(1);
    #pragma unroll
    for (int kk = 0; kk < 2; ++kk)
      #pragma unroll
      for (int i = 0; i < 4; ++i)
        #pragma unroll
        for (int j = 0; j < 2; ++j)
          acc[4 + i][j] = __builtin_amdgcn_mfma_f32_16x16x32_bf16(a1[i][kk], b0[j][kk], acc[4 + i][j], 0, 0, 0);
    __builtin_amdgcn_s_setprio(0);
    asm volatile("s_barrier" ::: "memory");

    // ================= phase 2: quad (1,1) =================
    #pragma unroll
    for (int j = 0; j < 2; ++j)
      #pragma unroll
      for (int kk = 0; kk < 2; ++kk)
        b1[j][kk] = *(const bf16x8*)(bb + ((2 + j)*2 + kk) * 1024);
    if (t + 2 < NT) stage_half(A0 + (t+2)*64, buf*65536);
    asm volatile("s_barrier" ::: "memory");
    __builtin_amdgcn_s_setprio(1);
    #pragma unroll
    for (int kk = 0; kk < 2; ++kk)
      #pragma unroll
      for (int i = 0; i < 4; ++i)
        #pragma unroll
        for (int j = 0; j < 2; ++j)
          acc[4 + i][2 + j] = __builtin_amdgcn_mfma_f32_16x16x32_bf16(a1[i][kk], b1[j][kk], acc[4 + i][2 + j], 0, 0, 0);
    __builtin_amdgcn_s_setprio(0);
    asm volatile("s_barrier" ::: "memory");

    // ================= phase 3: quad (0,1) =================
    if (t + 2 < NT) stage_half(A1 + (t+2)*64, buf*65536 + 16384);
    asm volatile("s_barrier" ::: "memory");
    __builtin_amdgcn_s_setprio(1);
    #pragma unroll
    for (int kk = 0; kk < 2; ++kk)
      #pragma unroll
      for (int i = 0; i < 4; ++i)
        #pragma unroll
        for (int j = 0; j < 2; ++j)
          acc[i][2 + j] = __builtin_amdgcn_mfma_f32_16x16x32_bf16(a0[i][kk], b1[j][kk], acc[i][2 + j], 0, 0, 0);
    __builtin_amdgcn_s_setprio(0);
    if (t + 2 < NT) asm volatile("s_waitcnt vmcnt(4)" ::: "memory");
    else            asm volatile("s_waitcnt vmcnt(0)" ::: "memory");
    asm volatile("s_barrier" ::: "memory");
  }

  // ---- epilogue ----
  #pragma unroll
  for (int i = 0; i < 8; ++i)
    #pragma unroll
    for (int j = 0; j < 4; ++j)
      #pragma unroll
      for (int r = 0; r < 4; ++r) {
        int row = m0 + wm*128 + i*16 + kq*4 + r;
        int col = n0 + wn*64 + j*16 + lrow;
        size_t idx = (size_t)row * N + col;
        float v = acc[i][j][r];
        if (EPI == 0) {
          Cb[idx] = f2bf(v);
        } else if (EPI == 1) {
          Cf[idx] = v + add[idx];
        } else {
          float g = 0.5f * v * (1.0f + erff(v * 0.70710678118654752f));
          Cb[idx] = f2bf(g);
        }
      }
}

// ---- prep: split heads + per-head exp_map ----
__global__ void prep_qk(const u16* __restrict__ in, const float* __restrict__ headK,
                        u16* __restrict__ Lout, float* __restrict__ l0,
                        int instride, int off) {
  int gid = blockIdx.x * 4 + (threadIdx.x >> 6);
  int lane = threadIdx.x & 63;
  int b = gid >> 15;
  int rem = gid & 32767;
  int h = rem >> 11;
  int s = rem & 2047;
  const u16* src = in + ((size_t)(b * SEQ + s)) * instride + off + h * DHEAD + lane * 2;
  float v0 = bf2f(src[0]), v1 = bf2f(src[1]);
  float nn = v0*v0 + v1*v1;
  #pragma unroll
  for (int m = 1; m < 64; m <<= 1) nn += __shfl_xor(nn, m, 64);
  float Kh = headK[h];
  float sk = sqrtf(-Kh);
  float a = sk * sqrtf(nn);
  float f = (a < 1e-6f) ? (1.0f + a*a*(1.0f/6.0f)) : (sinhf(a) / a);
  u16* dst = Lout + (size_t)gid * DHEAD + lane * 2;
  dst[0] = f2bf(f * v0);
  dst[1] = f2bf(f * v1);
  if (lane == 0) l0[gid] = sqrtf(-1.0f/Kh + f*f*nn);
}

// ---- vtrans ----
__global__ void vtrans(const u16* __restrict__ vb, u16* __restrict__ VT,
                       int instride, int off) {
  __shared__ u16 tile[32][33];
  int bh = blockIdx.x;
  int b = bh >> 4, h = bh & 15;
  int s0 = blockIdx.y * 32, d0 = blockIdx.z * 32;
  int tx = threadIdx.x, ty = threadIdx.y;
  #pragma unroll
  for (int i = 0; i < 4; ++i)
    tile[ty + 8*i][tx] = vb[((size_t)(b*SEQ + s0 + ty + 8*i)) * instride + off + h*DHEAD + d0 + tx];
  __syncthreads();
  #pragma unroll
  for (int i = 0; i < 4; ++i)
    VT[((size_t)bh*DHEAD + d0 + ty + 8*i) * SEQ + s0 + tx] = tile[tx][ty + 8*i];
}

// -------- flash attention v4: LDS double-buffer via gload16, swizzled, raw barriers --------
__global__ __launch_bounds__(256, 2) void attn_kernel(
    const u16* __restrict__ Ql, const u16* __restrict__ Kl,
    const u16* __restrict__ VT, const float* __restrict__ ql0,
    const float* __restrict__ kl0, const float* __restrict__ headK,
    u16* __restrict__ out) {
  __shared__ u16 klds[2][32 * 128];
  __shared__ u16 vlds[2][128 * 32];
  __shared__ u16 plds[4][32 * 36];
  const int tid = threadIdx.x, w = tid >> 6, lane = tid & 63;
  const int lrow = lane & 15, kq = lane >> 4;
  const int id = blockIdx.x;
  const int bh = id & 31;
  const int qb = 15 - (id >> 5);
  const int q0 = qb * 128 + w * 32;
  const int b = bh >> 4, h = bh & 15;
  const float Kh = headK[h];
  const float LOG2E = 1.44269504088896f;
  const float isd = 0.088388347648318447f;
  const float sc_mul = 2.0f * isd * LOG2E;
  const float sc_add = (-2.0f / Kh) * isd * LOG2E;

  const u16* kbase  = Kl + (size_t)bh * SEQ * DHEAD;
  const u16* vtbase = VT + (size_t)bh * DHEAD * SEQ;
  const float* kl0b = kl0 + (size_t)bh * SEQ;
  u16* pw = &plds[w][0];

  bf16x8 aq[2][4];
  const u16* qbase = Ql + ((size_t)bh * SEQ + q0) * DHEAD;
  #pragma unroll
  for (int m = 0; m < 2; ++m)
    #pragma unroll
    for (int dc = 0; dc < 4; ++dc)
      aq[m][dc] = *(const bf16x8*)&qbase[(size_t)(m*16 + lrow) * DHEAD + dc*32 + kq*8];
  float q0r[2][4];
  #pragma unroll
  for (int m = 0; m < 2; ++m)
    #pragma unroll
    for (int r = 0; r < 4; ++r)
      q0r[m][r] = ql0[(size_t)bh * SEQ + q0 + m*16 + kq*4 + r];

  auto stage = [&](int k0, int buf) {
    #pragma unroll
    for (int i = 0; i < 2; ++i) {
      int rl = w*8 + i*4 + (lane >> 4);
      int c = (lane & 15) ^ (rl & 15);
      gload16(kbase + ((size_t)(k0 + rl)) * DHEAD + c * 8,
              &klds[buf][(w*8 + i*4) * 128]);
    }
    #pragma unroll
    for (int i = 0; i < 2; ++i) {
      int rl = w*32 + i*16 + (lane >> 2);
      int c = (lane & 3) ^ ((rl >> 1) & 3);
      gload16(vtbase + (size_t)rl * SEQ + k0 + c * 8,
              &vlds[buf][(w*32 + i*16) * 32]);
    }
  };

  float lacc[2][4] = {};
  f32x4 o[2][8] = {};
  const int niter = qb * 4 + 4;

  stage(0, 0);
  for (int i = 0; i < niter; ++i) {
    const int k0 = i * 32, buf = i & 1;
    float kc0 = kl0b[k0 + lrow];
    float kc1 = kl0b[k0 + 16 + lrow];
    if (i + 1 < niter) {
      stage(k0 + 32, buf ^ 1);
      asm volatile("s_waitcnt vmcnt(4)" ::: "memory");
    } else {
      asm volatile("s_waitcnt vmcnt(0)" ::: "memory");
    }
    asm volatile("s_barrier" ::: "memory");

    f32x4 sc[2][2] = {};
    #pragma unroll
    for (int dc = 0; dc < 4; ++dc) {
      int c = dc*4 + kq;
      bf16x8 bk0 = *(const bf16x8*)&klds[buf][lrow*128        + (c ^ (lrow & 15)) * 8];
      bf16x8 bk1 = *(const bf16x8*)&klds[buf][(16 + lrow)*128 + (c ^ ((16 + lrow) & 15)) * 8];
      #pragma unroll
      for (int m = 0; m < 2; ++m) {
        sc[m][0] = __builtin_amdgcn_mfma_f32_16x16x32_bf16(aq[m][dc], bk0, sc[m][0], 0, 0, 0);
        sc[m][1] = __builtin_amdgcn_mfma_f32_16x16x32_bf16(aq[m][dc], bk1, sc[m][1], 0, 0, 0);
      }
    }
    #pragma unroll
    for (int m = 0; m < 2; ++m)
      #pragma unroll
      for (int r = 0; r < 4; ++r) {
        int qg = q0 + m*16 + kq*4 + r;
        float p0 = exp2f((sc[m][0][r] - q0r[m][r] * kc0) * sc_mul + sc_add);
        float p1 = exp2f((sc[m][1][r] - q0r[m][r] * kc1) * sc_mul + sc_add);
        p0 = (k0 + lrow      <= qg) ? p0 : 0.f;
        p1 = (k0 + 16 + lrow <= qg) ? p1 : 0.f;
        lacc[m][r] += p0 + p1;
        pw[(m*16 + kq*4 + r) * 36 + lrow]      = f2bf(p0);
        pw[(m*16 + kq*4 + r) * 36 + 16 + lrow] = f2bf(p1);
      }
    bf16x8 ap0 = *(const bf16x8*)&pw[(size_t)lrow * 36 + kq*8];
    bf16x8 ap1 = *(const bf16x8*)&pw[(size_t)(16 + lrow) * 36 + kq*8];
    int vc = (kq ^ ((lrow >> 1) & 3)) * 8;
    #pragma unroll
    for (int n = 0; n < 8; ++n) {
      bf16x8 bv = *(const bf16x8*)&vlds[buf][(n*16 + lrow) * 32 + vc];
      o[0][n] = __builtin_amdgcn_mfma_f32_16x16x32_bf16(ap0, bv, o[0][n], 0, 0, 0);
      o[1][n] = __builtin_amdgcn_mfma_f32_16x16x32_bf16(ap1, bv, o[1][n], 0, 0, 0);
    }
    asm volatile("s_barrier" ::: "memory");
  }

  float rcl[2][4];
  #pragma unroll
  for (int m = 0; m < 2; ++m)
    #pragma unroll
    for (int r = 0; r < 4; ++r) {
      float s = lacc[m][r];
      #pragma unroll
      for (int mm = 1; mm < 16; mm <<= 1) s += __shfl_xor(s, mm, 16);
      rcl[m][r] = 1.0f / s;
    }
  #pragma unroll
  for (int m = 0; m < 2; ++m)
    #pragma unroll
    for (int n = 0; n < 8; ++n)
      #pragma unroll
      for (int r = 0; r < 4; ++r) {
        int qg = q0 + m*16 + kq*4 + r;
        out[((size_t)b * SEQ + qg) * DMODEL + h * DHEAD + n*16 + lrow] =
            f2bf(o[m][n][r] * rcl[m][r]);
      }
}

extern "C" void kernel_launch(void* const* d_in, const int* in_sizes, int n_in,
                              void* d_out, int out_size, void* d_ws, size_t ws_size,
                              hipStream_t stream) {
  const float* x      = (const float*)d_in[0];
  const float* scale1 = (const float*)d_in[2];
  const float* scale2 = (const float*)d_in[3];
  const float* Wq     = (const float*)d_in[4];
  const float* Wk     = (const float*)d_in[5];
  const float* Wv     = (const float*)d_in[6];
  const float* Wo     = (const float*)d_in[7];
  const float* headK  = (const float*)d_in[8];
  const float* W1     = (const float*)d_in[9];
  const float* W2     = (const float*)d_in[10];
  float* out = (float*)d_out;

  char* p = (char*)d_ws;
  size_t off = 0;
  auto take = [&](size_t bytes) -> char* {
    char* r = p + off;
    off += (bytes + 255) & ~(size_t)255;
    return r;
  };
  u16* WqT = (u16*)take((size_t)DMODEL*DMODEL*2);   // WqT/WkT/WvT contiguous => (6144,2048)
  u16* WkT = (u16*)take((size_t)DMODEL*DMODEL*2);
  u16* WvT = (u16*)take((size_t)DMODEL*DMODEL*2);
  u16* WoT = (u16*)take((size_t)DMODEL*DMODEL*2);
  u16* W1T = (u16*)take((size_t)DMODEL*DFFN*2);
  u16* W2T = (u16*)take((size_t)DMODEL*DFFN*2);
  float* vres = (float*)take((size_t)MROWS*DMODEL*4);   // v1 -> u2 -> u3 (in place)
  u16* tbuf = (u16*)take((size_t)MROWS*DMODEL*2);       // t1, attn_out, t2
  u16* qkvb = (u16*)take((size_t)MROWS*3*DMODEL*2);     // fused QKV out (4096 x 6144)
  u16* Qlb  = (u16*)take((size_t)MROWS*DMODEL*2);       // qkvb+Qlb = 64MB => FFN hidden
  u16* Klb  = (u16*)take((size_t)MROWS*DMODEL*2);
  u16* VTb  = (u16*)take((size_t)MROWS*DMODEL*2);
  float* q0b = (float*)take((size_t)NB*NHEAD*SEQ*4);
  float* k0b = (float*)take((size_t)NB*NHEAD*SEQ*4);
  u16* hbuf = qkvb;     // reuse qkvb..Qlb contiguous 64MB = MROWS*DFFN bf16
  u16* attnout = tbuf;  // t1 consumed by QKV gemm before attention writes here

  dim3 tb(32, 8);
  transpose_w<<<dim3(DMODEL/32, DMODEL/32), tb, 0, stream>>>(Wq, WqT, DMODEL, DMODEL);
  transpose_w<<<dim3(DMODEL/32, DMODEL/32), tb, 0, stream>>>(Wk, WkT, DMODEL, DMODEL);
  transpose_w<<<dim3(DMODEL/32, DMODEL/32), tb, 0, stream>>>(Wv, WvT, DMODEL, DMODEL);
  transpose_w<<<dim3(DMODEL/32, DMODEL/32), tb, 0, stream>>>(Wo, WoT, DMODEL, DMODEL);
  transpose_w<<<dim3(DFFN/32,   DMODEL/32), tb, 0, stream>>>(W1, W1T, DMODEL, DFFN);
  transpose_w<<<dim3(DMODEL/32, DFFN/32),   tb, 0, stream>>>(W2, W2T, DFFN, DMODEL);

  ln_first<<<MROWS, 256, 0, stream>>>(x, scale1, vres, tbuf);

  // fused QKV: M=4096, N=6144, K=2048 -> 384 blocks
  gemm256<0><<<dim3((3*DMODEL/256)*(MROWS/256)), 512, 0, stream>>>(
      tbuf, WqT, qkvb, nullptr, nullptr, MROWS, 3*DMODEL, DMODEL);

  prep_qk<<<NB*NHEAD*SEQ/4, 256, 0, stream>>>(qkvb, headK, Qlb, q0b, 3*DMODEL, 0);
  prep_qk<<<NB*NHEAD*SEQ/4, 256, 0, stream>>>(qkvb, headK, Klb, k0b, 3*DMODEL, DMODEL);
  vtrans<<<dim3(NB*NHEAD, SEQ/32, DHEAD/32), tb, 0, stream>>>(qkvb, VTb, 3*DMODEL, 2*DMODEL);

  attn_kernel<<<dim3(512), 256, 0, stream>>>(Qlb, Klb, VTb, q0b, k0b, headK, attnout);

  // Wo: M=4096, N=2048, K=2048 -> 128 blocks
  gemm256<1><<<dim3((DMODEL/256)*(MROWS/256)), 512, 0, stream>>>(
      attnout, WoT, nullptr, vres, vres, MROWS, DMODEL, DMODEL);

  rms_mid<<<MROWS, 256, 0, stream>>>(vres, scale2, tbuf);

  // W1 + gelu: M=4096, N=8192, K=2048 -> 512 blocks
  gemm256<2><<<dim3((DFFN/256)*(MROWS/256)), 512, 0, stream>>>(
      tbuf, W1T, hbuf, nullptr, nullptr, MROWS, DFFN, DMODEL);

  // W2: M=4096, N=2048, K=8192 -> 128 blocks
  gemm256<1><<<dim3((DMODEL/256)*(MROWS/256)), 512, 0, stream>>>(
      hbuf, W2T, nullptr, vres, vres, MROWS, DMODEL, DFFN);

  final_exp<<<MROWS, 256, 0, stream>>>(vres, out);

  (void)in_sizes; (void)n_in; (void)out_size; (void)ws_size;
}

// Round 4
// 905.143 us; speedup vs baseline: 1.1217x; 1.1079x over previous
//
#include <hip/hip_runtime.h>
#include <stdint.h>

typedef unsigned short u16;
typedef __attribute__((ext_vector_type(8))) short bf16x8;
typedef __attribute__((ext_vector_type(4))) float f32x4;

#define SEQ    2048
#define NB     2
#define NHEAD  16
#define DHEAD  128
#define DMODEL 2048
#define DFFN   8192
#define MROWS  4096   // NB*SEQ

__device__ __forceinline__ u16 f2bf(float x) {
  union { float f; uint32_t u; } v; v.f = x;
  return (u16)((v.u + 0x7fffu + ((v.u >> 16) & 1u)) >> 16);
}
__device__ __forceinline__ float bf2f(u16 h) {
  union { uint32_t u; float f; } v; v.u = ((uint32_t)h) << 16;
  return v.f;
}
__device__ __forceinline__ void gload16(const void* g, void* l) {
  __builtin_amdgcn_global_load_lds((const __attribute__((address_space(1))) void*)g,
                                   (__attribute__((address_space(3))) void*)l,
                                   16, 0, 0);
}
__device__ __forceinline__ float blockSum256(float v) {
  __shared__ float red[4];
  #pragma unroll
  for (int m = 1; m < 64; m <<= 1) v += __shfl_xor(v, m, 64);
  int w = threadIdx.x >> 6;
  if ((threadIdx.x & 63) == 0) red[w] = v;
  __syncthreads();
  float s = red[0] + red[1] + red[2] + red[3];
  __syncthreads();
  return s;
}

// ---------------- weight transpose fp32 (R,C) -> bf16 (C,R) ----------------
__global__ void transpose_w(const float* __restrict__ in, u16* __restrict__ out, int R, int C) {
  __shared__ float tile[32][33];
  int c0 = blockIdx.x * 32, r0 = blockIdx.y * 32;
  int tx = threadIdx.x, ty = threadIdx.y;
  #pragma unroll
  for (int i = 0; i < 4; ++i)
    tile[ty + 8*i][tx] = in[(size_t)(r0 + ty + 8*i) * C + c0 + tx];
  __syncthreads();
  #pragma unroll
  for (int i = 0; i < 4; ++i)
    out[(size_t)(c0 + ty + 8*i) * R + r0 + tx] = f2bf(tile[tx][ty + 8*i]);
}

// ---- ln_first: x(B,S,2049) -> v1 = log_map(x) fp32, t1 = scale*v1/rms bf16 ----
__global__ void ln_first(const float* __restrict__ x, const float* __restrict__ scale,
                         float* __restrict__ v1, u16* __restrict__ t1) {
  int row = blockIdx.x;
  const float* xr = x + (size_t)row * (DMODEL + 1) + 1;
  float vals[8]; float ss = 0.f;
  #pragma unroll
  for (int i = 0; i < 8; ++i) {
    int idx = threadIdx.x + 256 * i;
    vals[i] = xr[idx];
    ss += vals[i] * vals[i];
  }
  ss = blockSum256(ss);
  float n = sqrtf(ss);
  float f = (n < 1e-6f) ? (1.0f - n * n * (1.0f/6.0f)) : (asinhf(n) / n);
  float rms = sqrtf(f * f * ss * (1.0f / DMODEL) + 1e-6f);
  float ir = 1.0f / rms;
  #pragma unroll
  for (int i = 0; i < 8; ++i) {
    int idx = threadIdx.x + 256 * i;
    float v = f * vals[i];
    v1[(size_t)row * DMODEL + idx] = v;
    t1[(size_t)row * DMODEL + idx] = f2bf(scale[idx] * v * ir);
  }
}

// ---- rms_mid3: u = v + p0 + p1 (write back); t = scale*u/rms(u) ----
__global__ void rms_mid3(float* __restrict__ u, const float* __restrict__ p0,
                         const float* __restrict__ p1, const float* __restrict__ scale,
                         u16* __restrict__ t) {
  int row = blockIdx.x;
  size_t base = (size_t)row * DMODEL;
  float vals[8]; float ss = 0.f;
  #pragma unroll
  for (int i = 0; i < 8; ++i) {
    int idx = threadIdx.x + 256*i;
    float v = u[base + idx] + p0[base + idx] + p1[base + idx];
    vals[i] = v; ss += v*v;
  }
  ss = blockSum256(ss);
  float ir = 1.0f / sqrtf(ss * (1.0f / DMODEL) + 1e-6f);
  #pragma unroll
  for (int i = 0; i < 8; ++i) {
    int idx = threadIdx.x + 256*i;
    u[base + idx] = vals[i];
    t[base + idx] = f2bf(scale[idx]*vals[i]*ir);
  }
}

// ---- final_exp3: out = exp_map_stable(u + p0 + p1), row length 2049 ----
__global__ void final_exp3(const float* __restrict__ u, const float* __restrict__ p0,
                           const float* __restrict__ p1, float* __restrict__ out) {
  int row = blockIdx.x;
  size_t base = (size_t)row * DMODEL;
  float vals[8]; float ss = 0.f;
  #pragma unroll
  for (int i = 0; i < 8; ++i) {
    int idx = threadIdx.x + 256*i;
    float v = u[base + idx] + p0[base + idx] + p1[base + idx];
    vals[i] = v; ss += v*v;
  }
  ss = blockSum256(ss);
  float n = sqrtf(ss);
  float f = (n < 1e-6f) ? (1.0f + n*n*(1.0f/6.0f)) : (sinhf(n)/n);
  float* orow = out + (size_t)row * (DMODEL + 1);
  if (threadIdx.x == 0) orow[0] = sqrtf(1.0f + f*f*ss);
  #pragma unroll
  for (int i = 0; i < 8; ++i) { int idx = threadIdx.x + 256*i; orow[1+idx] = f*vals[i]; }
}

// ============================================================================
// GEMM 256x256 tile, BK=64, 8 waves (2M x 4N), 8-phase counted-vmcnt schedule
// (T3+T4), st_16x32 LDS swizzle (T2), setprio around MFMA (T5), XCD swizzle (T1).
// LDS: STATIC 131072 B = 2 buffers x (A 256x64 + B 256x64) bf16.
// K-split support: blockIdx.y selects a K-half of length kHalf (elements);
// EPI 3 writes raw fp32 partials to Cf + y*M*N (reduction fused downstream).
// EPI 0: store bf16; EPI 2: gelu -> bf16. K is the row stride (full K).
// ============================================================================
template<int EPI>
__global__ __launch_bounds__(512, 2) void gemm256(
    const u16* __restrict__ A, const u16* __restrict__ Bt,
    u16* __restrict__ Cb, float* Cf,
    int M, int N, int K, int kHalf)
{
  __shared__ __attribute__((aligned(128))) char smem[131072];
  const int tid = threadIdx.x;
  const int w = tid >> 6, lane = tid & 63;
  const int lrow = lane & 15, kq = lane >> 4;
  const int wm = w >> 2, wn = w & 3;

  // K-split select
  const int ksel = blockIdx.y;
  A  += (size_t)ksel * kHalf;
  Bt += (size_t)ksel * kHalf;
  if (EPI == 3) Cf += (size_t)ksel * M * N;
  const int NT = kHalf >> 6;      // K-tiles in this split

  // T1: XCD-aware bijective swizzle (gridDim.x is a multiple of 8)
  const int nwg = gridDim.x;
  const int cpx = nwg >> 3;
  const int sid = (blockIdx.x & 7) * cpx + (blockIdx.x >> 3);
  const int NX = N >> 8;
  const int bx = sid % NX, by = sid / NX;
  const int m0 = by * 256, n0 = bx * 256;

  // inverse-swizzled global source offsets for the 2 staging rounds
  size_t goff[2];
  #pragma unroll
  for (int r = 0; r < 2; ++r) {
    int L = r * 8192 + tid * 16;                  // linear LDS byte this thread fills
    int U = L ^ (((L >> 9) & 1) << 5);            // unswizzled byte offset in half
    int si = U >> 10;
    int row = (si >> 1) * 16 + ((U >> 6) & 15);
    int col = (si & 1) * 32 + ((U & 63) >> 1);
    goff[r] = (size_t)row * K + col;
  }
  auto stage_half = [&](const u16* g, int ldsOff) {
    #pragma unroll
    for (int r = 0; r < 2; ++r)
      gload16(g + goff[r], smem + ldsOff + r * 8192 + w * 1024);
  };

  const u16* A0 = A  + (size_t)m0 * K;
  const u16* A1 = A  + (size_t)(m0 + 128) * K;
  const u16* B0 = Bt + (size_t)n0 * K;
  const u16* B1 = Bt + (size_t)(n0 + 128) * K;

  // swizzled per-lane fragment byte offset within a half
  const int aoff = (lrow * 64 + kq * 16) ^ ((lrow & 8) << 2);

  f32x4 acc[8][4] = {};

  // ---- prologue: tile0 (4 halves) + tile1 A halves; wait tile0 resident ----
  stage_half(A0, 0);
  stage_half(A1, 16384);
  stage_half(B0, 32768);
  stage_half(B1, 49152);
  stage_half(A0 + 64, 65536);
  stage_half(A1 + 64, 65536 + 16384);
  asm volatile("s_waitcnt vmcnt(4)" ::: "memory");
  asm volatile("s_barrier" ::: "memory");

  for (int t = 0; t < NT; ++t) {
    const int buf = t & 1;
    const char* ab = smem + buf * 65536 + wm * 16384 + aoff;
    const char* bb = smem + buf * 65536 + 32768 + (wn >> 1) * 16384 + (wn & 1) * 8192 + aoff;
    bf16x8 a0[4][2], a1[4][2], b0[2][2], b1[2][2];

    // ================= phase 0: quad (0,0) =================
    #pragma unroll
    for (int i = 0; i < 4; ++i)
      #pragma unroll
      for (int kk = 0; kk < 2; ++kk)
        a0[i][kk] = *(const bf16x8*)(ab + (i*2 + kk) * 1024);
    #pragma unroll
    for (int j = 0; j < 2; ++j)
      #pragma unroll
      for (int kk = 0; kk < 2; ++kk)
        b0[j][kk] = *(const bf16x8*)(bb + (j*2 + kk) * 1024);
    if (t + 1 < NT) stage_half(B0 + (t+1)*64, (buf^1)*65536 + 32768);
    asm volatile("s_barrier" ::: "memory");
    __builtin_amdgcn_s_setprio(1);
    #pragma unroll
    for (int kk = 0; kk < 2; ++kk)
      #pragma unroll
      for (int i = 0; i < 4; ++i)
        #pragma unroll
        for (int j = 0; j < 2; ++j)
          acc[i][j] = __builtin_amdgcn_mfma_f32_16x16x32_bf16(a0[i][kk], b0[j][kk], acc[i][j], 0, 0, 0);
    __builtin_amdgcn_s_setprio(0);
    asm volatile("s_barrier" ::: "memory");

    // ================= phase 1: quad (1,0) =================
    #pragma unroll
    for (int i = 0; i < 4; ++i)
      #pragma unroll
      for (int kk = 0; kk < 2; ++kk)
        a1[i][kk] = *(const bf16x8*)(ab + ((4 + i)*2 + kk) * 1024);
    if (t + 1 < NT) stage_half(B1 + (t+1)*64, (buf^1)*65536 + 49152);
    asm volatile("s_barrier" ::: "memory");
    __builtin_amdgcn_s_setprio(1);
    #pragma unroll
    for (int kk = 0; kk < 2; ++kk)
      #pragma unroll
      for (int i = 0; i < 4; ++i)
        #pragma unroll
        for (int j = 0; j < 2; ++j)
          acc[4 + i][j] = __builtin_amdgcn_mfma_f32_16x16x32_bf16(a1[i][kk], b0[j][kk], acc[4 + i][j], 0, 0, 0);
    __builtin_amdgcn_s_setprio(0);
    asm volatile("s_barrier" ::: "memory");

    // ================= phase 2: quad (1,1) =================
    #pragma unroll
    for (int j = 0; j < 2; ++j)
      #pragma unroll
      for (int kk = 0; kk < 2; ++kk)
        b1[j][kk] = *(const bf16x8*)(bb + ((2 + j)*2 + kk) * 1024);
    if (t + 2 < NT) stage_half(A0 + (t+2)*64, buf*65536);
    asm volatile("s_barrier" ::: "memory");
    __builtin_amdgcn_s_setprio(1);
    #pragma unroll
    for (int kk = 0; kk < 2; ++kk)
      #pragma unroll
      for (int i = 0; i < 4; ++i)
        #pragma unroll
        for (int j = 0; j < 2; ++j)
          acc[4 + i][2 + j] = __builtin_amdgcn_mfma_f32_16x16x32_bf16(a1[i][kk], b1[j][kk], acc[4 + i][2 + j], 0, 0, 0);
    __builtin_amdgcn_s_setprio(0);
    asm volatile("s_barrier" ::: "memory");

    // ================= phase 3: quad (0,1) =================
    if (t + 2 < NT) stage_half(A1 + (t+2)*64, buf*65536 + 16384);
    asm volatile("s_barrier" ::: "memory");
    __builtin_amdgcn_s_setprio(1);
    #pragma unroll
    for (int kk = 0; kk < 2; ++kk)
      #pragma unroll
      for (int i = 0; i < 4; ++i)
        #pragma unroll
        for (int j = 0; j < 2; ++j)
          acc[i][2 + j] = __builtin_amdgcn_mfma_f32_16x16x32_bf16(a0[i][kk], b1[j][kk], acc[i][2 + j], 0, 0, 0);
    __builtin_amdgcn_s_setprio(0);
    if (t + 2 < NT) asm volatile("s_waitcnt vmcnt(4)" ::: "memory");
    else            asm volatile("s_waitcnt vmcnt(0)" ::: "memory");
    asm volatile("s_barrier" ::: "memory");
  }

  // ---- epilogue ----
  #pragma unroll
  for (int i = 0; i < 8; ++i)
    #pragma unroll
    for (int j = 0; j < 4; ++j)
      #pragma unroll
      for (int r = 0; r < 4; ++r) {
        int row = m0 + wm*128 + i*16 + kq*4 + r;
        int col = n0 + wn*64 + j*16 + lrow;
        size_t idx = (size_t)row * N + col;
        float v = acc[i][j][r];
        if (EPI == 0) {
          Cb[idx] = f2bf(v);
        } else if (EPI == 3) {
          Cf[idx] = v;
        } else {
          float g = 0.5f * v * (1.0f + erff(v * 0.70710678118654752f));
          Cb[idx] = f2bf(g);
        }
      }
}

// ---- prep: split heads + per-head exp_map ----
__global__ void prep_qk(const u16* __restrict__ in, const float* __restrict__ headK,
                        u16* __restrict__ Lout, float* __restrict__ l0,
                        int instride, int off) {
  int gid = blockIdx.x * 4 + (threadIdx.x >> 6);
  int lane = threadIdx.x & 63;
  int b = gid >> 15;
  int rem = gid & 32767;
  int h = rem >> 11;
  int s = rem & 2047;
  const u16* src = in + ((size_t)(b * SEQ + s)) * instride + off + h * DHEAD + lane * 2;
  float v0 = bf2f(src[0]), v1 = bf2f(src[1]);
  float nn = v0*v0 + v1*v1;
  #pragma unroll
  for (int m = 1; m < 64; m <<= 1) nn += __shfl_xor(nn, m, 64);
  float Kh = headK[h];
  float sk = sqrtf(-Kh);
  float a = sk * sqrtf(nn);
  float f = (a < 1e-6f) ? (1.0f + a*a*(1.0f/6.0f)) : (sinhf(a) / a);
  u16* dst = Lout + (size_t)gid * DHEAD + lane * 2;
  dst[0] = f2bf(f * v0);
  dst[1] = f2bf(f * v1);
  if (lane == 0) l0[gid] = sqrtf(-1.0f/Kh + f*f*nn);
}

// ---- vtrans ----
__global__ void vtrans(const u16* __restrict__ vb, u16* __restrict__ VT,
                       int instride, int off) {
  __shared__ u16 tile[32][33];
  int bh = blockIdx.x;
  int b = bh >> 4, h = bh & 15;
  int s0 = blockIdx.y * 32, d0 = blockIdx.z * 32;
  int tx = threadIdx.x, ty = threadIdx.y;
  #pragma unroll
  for (int i = 0; i < 4; ++i)
    tile[ty + 8*i][tx] = vb[((size_t)(b*SEQ + s0 + ty + 8*i)) * instride + off + h*DHEAD + d0 + tx];
  __syncthreads();
  #pragma unroll
  for (int i = 0; i < 4; ++i)
    VT[((size_t)bh*DHEAD + d0 + ty + 8*i) * SEQ + s0 + tx] = tile[tx][ty + 8*i];
}

// -------- flash attention v4: LDS double-buffer via gload16, swizzled, raw barriers --------
__global__ __launch_bounds__(256, 2) void attn_kernel(
    const u16* __restrict__ Ql, const u16* __restrict__ Kl,
    const u16* __restrict__ VT, const float* __restrict__ ql0,
    const float* __restrict__ kl0, const float* __restrict__ headK,
    u16* __restrict__ out) {
  __shared__ u16 klds[2][32 * 128];
  __shared__ u16 vlds[2][128 * 32];
  __shared__ u16 plds[4][32 * 36];
  const int tid = threadIdx.x, w = tid >> 6, lane = tid & 63;
  const int lrow = lane & 15, kq = lane >> 4;
  const int id = blockIdx.x;
  const int bh = id & 31;
  const int qb = 15 - (id >> 5);
  const int q0 = qb * 128 + w * 32;
  const int b = bh >> 4, h = bh & 15;
  const float Kh = headK[h];
  const float LOG2E = 1.44269504088896f;
  const float isd = 0.088388347648318447f;
  const float sc_mul = 2.0f * isd * LOG2E;
  const float sc_add = (-2.0f / Kh) * isd * LOG2E;

  const u16* kbase  = Kl + (size_t)bh * SEQ * DHEAD;
  const u16* vtbase = VT + (size_t)bh * DHEAD * SEQ;
  const float* kl0b = kl0 + (size_t)bh * SEQ;
  u16* pw = &plds[w][0];

  bf16x8 aq[2][4];
  const u16* qbase = Ql + ((size_t)bh * SEQ + q0) * DHEAD;
  #pragma unroll
  for (int m = 0; m < 2; ++m)
    #pragma unroll
    for (int dc = 0; dc < 4; ++dc)
      aq[m][dc] = *(const bf16x8*)&qbase[(size_t)(m*16 + lrow) * DHEAD + dc*32 + kq*8];
  float q0r[2][4];
  #pragma unroll
  for (int m = 0; m < 2; ++m)
    #pragma unroll
    for (int r = 0; r < 4; ++r)
      q0r[m][r] = ql0[(size_t)bh * SEQ + q0 + m*16 + kq*4 + r];

  auto stage = [&](int k0, int buf) {
    #pragma unroll
    for (int i = 0; i < 2; ++i) {
      int rl = w*8 + i*4 + (lane >> 4);
      int c = (lane & 15) ^ (rl & 15);
      gload16(kbase + ((size_t)(k0 + rl)) * DHEAD + c * 8,
              &klds[buf][(w*8 + i*4) * 128]);
    }
    #pragma unroll
    for (int i = 0; i < 2; ++i) {
      int rl = w*32 + i*16 + (lane >> 2);
      int c = (lane & 3) ^ ((rl >> 1) & 3);
      gload16(vtbase + (size_t)rl * SEQ + k0 + c * 8,
              &vlds[buf][(w*32 + i*16) * 32]);
    }
  };

  float lacc[2][4] = {};
  f32x4 o[2][8] = {};
  const int niter = qb * 4 + 4;

  stage(0, 0);
  for (int i = 0; i < niter; ++i) {
    const int k0 = i * 32, buf = i & 1;
    float kc0 = kl0b[k0 + lrow];
    float kc1 = kl0b[k0 + 16 + lrow];
    if (i + 1 < niter) {
      stage(k0 + 32, buf ^ 1);
      asm volatile("s_waitcnt vmcnt(4)" ::: "memory");
    } else {
      asm volatile("s_waitcnt vmcnt(0)" ::: "memory");
    }
    asm volatile("s_barrier" ::: "memory");

    f32x4 sc[2][2] = {};
    #pragma unroll
    for (int dc = 0; dc < 4; ++dc) {
      int c = dc*4 + kq;
      bf16x8 bk0 = *(const bf16x8*)&klds[buf][lrow*128        + (c ^ (lrow & 15)) * 8];
      bf16x8 bk1 = *(const bf16x8*)&klds[buf][(16 + lrow)*128 + (c ^ ((16 + lrow) & 15)) * 8];
      #pragma unroll
      for (int m = 0; m < 2; ++m) {
        sc[m][0] = __builtin_amdgcn_mfma_f32_16x16x32_bf16(aq[m][dc], bk0, sc[m][0], 0, 0, 0);
        sc[m][1] = __builtin_amdgcn_mfma_f32_16x16x32_bf16(aq[m][dc], bk1, sc[m][1], 0, 0, 0);
      }
    }
    #pragma unroll
    for (int m = 0; m < 2; ++m)
      #pragma unroll
      for (int r = 0; r < 4; ++r) {
        int qg = q0 + m*16 + kq*4 + r;
        float p0 = exp2f((sc[m][0][r] - q0r[m][r] * kc0) * sc_mul + sc_add);
        float p1 = exp2f((sc[m][1][r] - q0r[m][r] * kc1) * sc_mul + sc_add);
        p0 = (k0 + lrow      <= qg) ? p0 : 0.f;
        p1 = (k0 + 16 + lrow <= qg) ? p1 : 0.f;
        lacc[m][r] += p0 + p1;
        pw[(m*16 + kq*4 + r) * 36 + lrow]      = f2bf(p0);
        pw[(m*16 + kq*4 + r) * 36 + 16 + lrow] = f2bf(p1);
      }
    bf16x8 ap0 = *(const bf16x8*)&pw[(size_t)lrow * 36 + kq*8];
    bf16x8 ap1 = *(const bf16x8*)&pw[(size_t)(16 + lrow) * 36 + kq*8];
    int vc = (kq ^ ((lrow >> 1) & 3)) * 8;
    #pragma unroll
    for (int n = 0; n < 8; ++n) {
      bf16x8 bv = *(const bf16x8*)&vlds[buf][(n*16 + lrow) * 32 + vc];
      o[0][n] = __builtin_amdgcn_mfma_f32_16x16x32_bf16(ap0, bv, o[0][n], 0, 0, 0);
      o[1][n] = __builtin_amdgcn_mfma_f32_16x16x32_bf16(ap1, bv, o[1][n], 0, 0, 0);
    }
    asm volatile("s_barrier" ::: "memory");
  }

  float rcl[2][4];
  #pragma unroll
  for (int m = 0; m < 2; ++m)
    #pragma unroll
    for (int r = 0; r < 4; ++r) {
      float s = lacc[m][r];
      #pragma unroll
      for (int mm = 1; mm < 16; mm <<= 1) s += __shfl_xor(s, mm, 16);
      rcl[m][r] = 1.0f / s;
    }
  #pragma unroll
  for (int m = 0; m < 2; ++m)
    #pragma unroll
    for (int n = 0; n < 8; ++n)
      #pragma unroll
      for (int r = 0; r < 4; ++r) {
        int qg = q0 + m*16 + kq*4 + r;
        out[((size_t)b * SEQ + qg) * DMODEL + h * DHEAD + n*16 + lrow] =
            f2bf(o[m][n][r] * rcl[m][r]);
      }
}

extern "C" void kernel_launch(void* const* d_in, const int* in_sizes, int n_in,
                              void* d_out, int out_size, void* d_ws, size_t ws_size,
                              hipStream_t stream) {
  const float* x      = (const float*)d_in[0];
  const float* scale1 = (const float*)d_in[2];
  const float* scale2 = (const float*)d_in[3];
  const float* Wq     = (const float*)d_in[4];
  const float* Wk     = (const float*)d_in[5];
  const float* Wv     = (const float*)d_in[6];
  const float* Wo     = (const float*)d_in[7];
  const float* headK  = (const float*)d_in[8];
  const float* W1     = (const float*)d_in[9];
  const float* W2     = (const float*)d_in[10];
  float* out = (float*)d_out;

  char* p = (char*)d_ws;
  size_t off = 0;
  auto take = [&](size_t bytes) -> char* {
    char* r = p + off;
    off += (bytes + 255) & ~(size_t)255;
    return r;
  };
  u16* WqT = (u16*)take((size_t)DMODEL*DMODEL*2);   // WqT/WkT/WvT/WoT contiguous 32MB
  u16* WkT = (u16*)take((size_t)DMODEL*DMODEL*2);
  u16* WvT = (u16*)take((size_t)DMODEL*DMODEL*2);
  u16* WoT = (u16*)take((size_t)DMODEL*DMODEL*2);
  u16* W1T = (u16*)take((size_t)DMODEL*DFFN*2);
  u16* W2T = (u16*)take((size_t)DMODEL*DFFN*2);
  float* vres = (float*)take((size_t)MROWS*DMODEL*4);   // v1 -> u2 (in place)
  u16* tbuf = (u16*)take((size_t)MROWS*DMODEL*2);       // t1, attn_out, t2
  u16* qkvb = (u16*)take((size_t)MROWS*3*DMODEL*2);     // fused QKV out (4096 x 6144)
  u16* Qlb  = (u16*)take((size_t)MROWS*DMODEL*2);       // qkvb+Qlb = 64MB contiguous
  u16* Klb  = (u16*)take((size_t)MROWS*DMODEL*2);       // Klb+VTb = 32MB contiguous
  u16* VTb  = (u16*)take((size_t)MROWS*DMODEL*2);
  float* q0b = (float*)take((size_t)NB*NHEAD*SEQ*4);
  float* k0b = (float*)take((size_t)NB*NHEAD*SEQ*4);
  u16* hbuf = qkvb;     // reuse qkvb..Qlb contiguous 64MB = MROWS*DFFN bf16
  u16* attnout = tbuf;  // t1 consumed by QKV gemm before attention writes here

  // K-split partial buffers (scavenged, all 32MB fp32 = MROWS*DMODEL*4):
  //  - Wo partials: qkvb..Qlb (free after prep_qk/vtrans; consumed by rms_mid3
  //    before W1 overwrites the region as hbuf)
  float* PoA = (float*)qkvb;
  float* PoB = PoA + (size_t)MROWS*DMODEL;
  //  - W2 partials: WqT..WoT (weights dead) and Klb..VTb (attention dead)
  float* PfA = (float*)WqT;
  float* PfB = (float*)Klb;

  dim3 tb(32, 8);
  transpose_w<<<dim3(DMODEL/32, DMODEL/32), tb, 0, stream>>>(Wq, WqT, DMODEL, DMODEL);
  transpose_w<<<dim3(DMODEL/32, DMODEL/32), tb, 0, stream>>>(Wk, WkT, DMODEL, DMODEL);
  transpose_w<<<dim3(DMODEL/32, DMODEL/32), tb, 0, stream>>>(Wv, WvT, DMODEL, DMODEL);
  transpose_w<<<dim3(DMODEL/32, DMODEL/32), tb, 0, stream>>>(Wo, WoT, DMODEL, DMODEL);
  transpose_w<<<dim3(DFFN/32,   DMODEL/32), tb, 0, stream>>>(W1, W1T, DMODEL, DFFN);
  transpose_w<<<dim3(DMODEL/32, DFFN/32),   tb, 0, stream>>>(W2, W2T, DFFN, DMODEL);

  ln_first<<<MROWS, 256, 0, stream>>>(x, scale1, vres, tbuf);

  // fused QKV: M=4096, N=6144, K=2048 -> 384 blocks, no split
  gemm256<0><<<dim3((3*DMODEL/256)*(MROWS/256), 1), 512, 0, stream>>>(
      tbuf, WqT, qkvb, nullptr, MROWS, 3*DMODEL, DMODEL, DMODEL);

  prep_qk<<<NB*NHEAD*SEQ/4, 256, 0, stream>>>(qkvb, headK, Qlb, q0b, 3*DMODEL, 0);
  prep_qk<<<NB*NHEAD*SEQ/4, 256, 0, stream>>>(qkvb, headK, Klb, k0b, 3*DMODEL, DMODEL);
  vtrans<<<dim3(NB*NHEAD, SEQ/32, DHEAD/32), tb, 0, stream>>>(qkvb, VTb, 3*DMODEL, 2*DMODEL);

  attn_kernel<<<dim3(512), 256, 0, stream>>>(Qlb, Klb, VTb, q0b, k0b, headK, attnout);

  // Wo: M=4096, N=2048, K=2048, K-split 2 -> (128,2) blocks, fp32 partials
  gemm256<3><<<dim3((DMODEL/256)*(MROWS/256), 2), 512, 0, stream>>>(
      attnout, WoT, nullptr, PoA, MROWS, DMODEL, DMODEL, DMODEL/2);

  // u2 = v1 + PoA + PoB (in place) ; t2 = scale2 * u2 / rms
  rms_mid3<<<MROWS, 256, 0, stream>>>(vres, PoA, PoB, scale2, tbuf);

  // W1 + gelu: M=4096, N=8192, K=2048 -> 512 blocks, no split
  gemm256<2><<<dim3((DFFN/256)*(MROWS/256), 1), 512, 0, stream>>>(
      tbuf, W1T, hbuf, nullptr, MROWS, DFFN, DMODEL, DMODEL);

  // W2: M=4096, N=2048, K=8192, K-split 2 -> (128,2) blocks, fp32 partials
  // PfA gets K[0:4096), PfB = PfA + M*N... use separate buffers via ksel offset:
  // kernel adds ksel*M*N to Cf, so pass PfA and place PfB exactly M*N after it.
  // WqT..WoT is 32MB = M*N fp32 contiguous, Klb..VTb is the next partial.
  // They are NOT adjacent, so launch the two halves as one grid with Cf=PfA
  // only if PfB == PfA + M*N. It isn't; instead exploit that WqT..WoT (32MB)
  // and W1T (32MB) are contiguous: put both partials in WqT..W1T (64MB).
  // W1T is dead after the W1 GEMM above. PfB' = (float*)W1T.
  gemm256<3><<<dim3((DMODEL/256)*(MROWS/256), 2), 512, 0, stream>>>(
      hbuf, W2T, nullptr, PfA, MROWS, DMODEL, DFFN, DFFN/2);

  final_exp3<<<MROWS, 256, 0, stream>>>(vres, PfA, (float*)W1T, out);

  (void)PfB; (void)in_sizes; (void)n_in; (void)out_size; (void)ws_size;
}

// Round 5
// 899.635 us; speedup vs baseline: 1.1286x; 1.0061x over previous
//
#include <hip/hip_runtime.h>
#include <stdint.h>

typedef unsigned short u16;
typedef __attribute__((ext_vector_type(8))) short bf16x8;
typedef __attribute__((ext_vector_type(4))) float f32x4;

#define SEQ    2048
#define NB     2
#define NHEAD  16
#define DHEAD  128
#define DMODEL 2048
#define DFFN   8192
#define MROWS  4096   // NB*SEQ

__device__ __forceinline__ u16 f2bf(float x) {
  union { float f; uint32_t u; } v; v.f = x;
  return (u16)((v.u + 0x7fffu + ((v.u >> 16) & 1u)) >> 16);
}
__device__ __forceinline__ float bf2f(u16 h) {
  union { uint32_t u; float f; } v; v.u = ((uint32_t)h) << 16;
  return v.f;
}
__device__ __forceinline__ void gload16(const void* g, void* l) {
  __builtin_amdgcn_global_load_lds((const __attribute__((address_space(1))) void*)g,
                                   (__attribute__((address_space(3))) void*)l,
                                   16, 0, 0);
}
__device__ __forceinline__ float blockSum256(float v) {
  __shared__ float red[4];
  #pragma unroll
  for (int m = 1; m < 64; m <<= 1) v += __shfl_xor(v, m, 64);
  int w = threadIdx.x >> 6;
  if ((threadIdx.x & 63) == 0) red[w] = v;
  __syncthreads();
  float s = red[0] + red[1] + red[2] + red[3];
  __syncthreads();
  return s;
}

// ---------------- weight transpose fp32 (R,C) -> bf16 (C,R) ----------------
__global__ void transpose_w(const float* __restrict__ in, u16* __restrict__ out, int R, int C) {
  __shared__ float tile[32][33];
  int c0 = blockIdx.x * 32, r0 = blockIdx.y * 32;
  int tx = threadIdx.x, ty = threadIdx.y;
  #pragma unroll
  for (int i = 0; i < 4; ++i)
    tile[ty + 8*i][tx] = in[(size_t)(r0 + ty + 8*i) * C + c0 + tx];
  __syncthreads();
  #pragma unroll
  for (int i = 0; i < 4; ++i)
    out[(size_t)(c0 + ty + 8*i) * R + r0 + tx] = f2bf(tile[tx][ty + 8*i]);
}

// ---- ln_first: x(B,S,2049) -> v1 = log_map(x) fp32, t1 = scale*v1/rms bf16 ----
__global__ void ln_first(const float* __restrict__ x, const float* __restrict__ scale,
                         float* __restrict__ v1, u16* __restrict__ t1) {
  int row = blockIdx.x;
  const float* xr = x + (size_t)row * (DMODEL + 1) + 1;
  float vals[8]; float ss = 0.f;
  #pragma unroll
  for (int i = 0; i < 8; ++i) {
    int idx = threadIdx.x + 256 * i;
    vals[i] = xr[idx];
    ss += vals[i] * vals[i];
  }
  ss = blockSum256(ss);
  float n = sqrtf(ss);
  float f = (n < 1e-6f) ? (1.0f - n * n * (1.0f/6.0f)) : (asinhf(n) / n);
  float rms = sqrtf(f * f * ss * (1.0f / DMODEL) + 1e-6f);
  float ir = 1.0f / rms;
  #pragma unroll
  for (int i = 0; i < 8; ++i) {
    int idx = threadIdx.x + 256 * i;
    float v = f * vals[i];
    v1[(size_t)row * DMODEL + idx] = v;
    t1[(size_t)row * DMODEL + idx] = f2bf(scale[idx] * v * ir);
  }
}

// ---- rms_mid3: u = v + p0 + p1 (write back); t = scale*u/rms(u) ----
__global__ void rms_mid3(float* __restrict__ u, const float* __restrict__ p0,
                         const float* __restrict__ p1, const float* __restrict__ scale,
                         u16* __restrict__ t) {
  int row = blockIdx.x;
  size_t base = (size_t)row * DMODEL;
  float vals[8]; float ss = 0.f;
  #pragma unroll
  for (int i = 0; i < 8; ++i) {
    int idx = threadIdx.x + 256*i;
    float v = u[base + idx] + p0[base + idx] + p1[base + idx];
    vals[i] = v; ss += v*v;
  }
  ss = blockSum256(ss);
  float ir = 1.0f / sqrtf(ss * (1.0f / DMODEL) + 1e-6f);
  #pragma unroll
  for (int i = 0; i < 8; ++i) {
    int idx = threadIdx.x + 256*i;
    u[base + idx] = vals[i];
    t[base + idx] = f2bf(scale[idx]*vals[i]*ir);
  }
}

// ---- final_exp3: out = exp_map_stable(u + p0 + p1), row length 2049 ----
__global__ void final_exp3(const float* __restrict__ u, const float* __restrict__ p0,
                           const float* __restrict__ p1, float* __restrict__ out) {
  int row = blockIdx.x;
  size_t base = (size_t)row * DMODEL;
  float vals[8]; float ss = 0.f;
  #pragma unroll
  for (int i = 0; i < 8; ++i) {
    int idx = threadIdx.x + 256*i;
    float v = u[base + idx] + p0[base + idx] + p1[base + idx];
    vals[i] = v; ss += v*v;
  }
  ss = blockSum256(ss);
  float n = sqrtf(ss);
  float f = (n < 1e-6f) ? (1.0f + n*n*(1.0f/6.0f)) : (sinhf(n)/n);
  float* orow = out + (size_t)row * (DMODEL + 1);
  if (threadIdx.x == 0) orow[0] = sqrtf(1.0f + f*f*ss);
  #pragma unroll
  for (int i = 0; i < 8; ++i) { int idx = threadIdx.x + 256*i; orow[1+idx] = f*vals[i]; }
}

// ============================================================================
// GEMM 256x256 tile, BK=64, 8 waves (2M x 4N), read-ahead pipelined phases.
// Quadrant order (0,0),(0,1),(1,0),(1,1): each phase issues the NEXT phase's
// ds_reads BEFORE its MFMA, so LDS service overlaps the MFMA burst (compiler
// emits counted lgkmcnt: older reads drained, new ones left in flight).
// 4 barriers/K-tile (was 8). Staging per tile t: p0/p1 -> B(t+1) halves into
// buf^1; p2/p3 -> A(t+2) halves into buf. Waits:
//   p1 end: lgkmcnt(0)  (a1 reads drained => p2's A-h0 stage is WAR-safe)
//   p3 open: vmcnt(2) (drains A(t+1)+B(t+1), leaves Ah0(t+2)); vmcnt(0) on the
//            final staged tile. Then read a0',b0' of tile t+1 from buf^1.
// st_16x32 swizzle both-sides (T2), setprio (T5), XCD swizzle (T1) unchanged.
// K-split: blockIdx.y selects K-half; EPI 3 writes fp32 partials at +y*M*N.
// EPI 0: bf16 store; EPI 2: gelu -> bf16.
// ============================================================================
template<int EPI>
__global__ __launch_bounds__(512, 2) void gemm256(
    const u16* __restrict__ A, const u16* __restrict__ Bt,
    u16* __restrict__ Cb, float* Cf,
    int M, int N, int K, int kHalf)
{
  __shared__ __attribute__((aligned(128))) char smem[131072];
  const int tid = threadIdx.x;
  const int w = tid >> 6, lane = tid & 63;
  const int lrow = lane & 15, kq = lane >> 4;
  const int wm = w >> 2, wn = w & 3;

  // K-split select
  const int ksel = blockIdx.y;
  A  += (size_t)ksel * kHalf;
  Bt += (size_t)ksel * kHalf;
  if (EPI == 3) Cf += (size_t)ksel * M * N;
  const int NT = kHalf >> 6;      // K-tiles in this split

  // T1: XCD-aware bijective swizzle (gridDim.x is a multiple of 8)
  const int nwg = gridDim.x;
  const int cpx = nwg >> 3;
  const int sid = (blockIdx.x & 7) * cpx + (blockIdx.x >> 3);
  const int NX = N >> 8;
  const int bx = sid % NX, by = sid / NX;
  const int m0 = by * 256, n0 = bx * 256;

  // inverse-swizzled global source offsets for the 2 staging rounds
  size_t goff[2];
  #pragma unroll
  for (int r = 0; r < 2; ++r) {
    int L = r * 8192 + tid * 16;                  // linear LDS byte this thread fills
    int U = L ^ (((L >> 9) & 1) << 5);            // unswizzled byte offset in half
    int si = U >> 10;
    int row = (si >> 1) * 16 + ((U >> 6) & 15);
    int col = (si & 1) * 32 + ((U & 63) >> 1);
    goff[r] = (size_t)row * K + col;
  }
  auto stage_half = [&](const u16* g, int ldsOff) {
    #pragma unroll
    for (int r = 0; r < 2; ++r)
      gload16(g + goff[r], smem + ldsOff + r * 8192 + w * 1024);
  };

  const u16* A0 = A  + (size_t)m0 * K;
  const u16* A1 = A  + (size_t)(m0 + 128) * K;
  const u16* B0 = Bt + (size_t)n0 * K;
  const u16* B1 = Bt + (size_t)(n0 + 128) * K;

  // swizzled per-lane fragment byte offset within a half
  const int aoff = (lrow * 64 + kq * 16) ^ ((lrow & 8) << 2);

  f32x4 acc[8][4] = {};
  bf16x8 a0[4][2], a1[4][2], b0[2][2], b1[2][2];

  // ---- prologue: stage tile0 (A,B) + tile1 A halves; drain tile0; read a0,b0 ----
  stage_half(A0, 0);
  stage_half(A1, 16384);
  stage_half(B0, 32768);
  stage_half(B1, 49152);
  stage_half(A0 + 64, 65536);
  stage_half(A1 + 64, 65536 + 16384);
  asm volatile("s_waitcnt vmcnt(4)" ::: "memory");
  asm volatile("s_barrier" ::: "memory");
  {
    const char* ab = smem + wm * 16384 + aoff;
    const char* bb = smem + 32768 + (wn >> 1) * 16384 + (wn & 1) * 8192 + aoff;
    #pragma unroll
    for (int i = 0; i < 4; ++i)
      #pragma unroll
      for (int kk = 0; kk < 2; ++kk)
        a0[i][kk] = *(const bf16x8*)(ab + (i*2 + kk) * 1024);
    #pragma unroll
    for (int j = 0; j < 2; ++j)
      #pragma unroll
      for (int kk = 0; kk < 2; ++kk)
        b0[j][kk] = *(const bf16x8*)(bb + (j*2 + kk) * 1024);
  }

  for (int t = 0; t < NT; ++t) {
    const int buf = t & 1;
    const char* ab  = smem + buf * 65536 + wm * 16384 + aoff;
    const char* bb  = smem + buf * 65536 + 32768 + (wn >> 1) * 16384 + (wn & 1) * 8192 + aoff;
    const char* abn = smem + (buf^1) * 65536 + wm * 16384 + aoff;
    const char* bbn = smem + (buf^1) * 65536 + 32768 + (wn >> 1) * 16384 + (wn & 1) * 8192 + aoff;

    // ===== p0: MFMA(a0,b0) quad(0,0); read b1; stage Bh0(t+1) =====
    asm volatile("s_barrier" ::: "memory");
    #pragma unroll
    for (int j = 0; j < 2; ++j)
      #pragma unroll
      for (int kk = 0; kk < 2; ++kk)
        b1[j][kk] = *(const bf16x8*)(bb + ((2 + j)*2 + kk) * 1024);
    if (t + 1 < NT) stage_half(B0 + (t+1)*64, (buf^1)*65536 + 32768);
    __builtin_amdgcn_s_setprio(1);
    #pragma unroll
    for (int kk = 0; kk < 2; ++kk)
      #pragma unroll
      for (int i = 0; i < 4; ++i)
        #pragma unroll
        for (int j = 0; j < 2; ++j)
          acc[i][j] = __builtin_amdgcn_mfma_f32_16x16x32_bf16(a0[i][kk], b0[j][kk], acc[i][j], 0, 0, 0);
    __builtin_amdgcn_s_setprio(0);

    // ===== p1: MFMA(a0,b1) quad(0,1); read a1; stage Bh1(t+1); drain lgkm =====
    asm volatile("s_barrier" ::: "memory");
    #pragma unroll
    for (int i = 0; i < 4; ++i)
      #pragma unroll
      for (int kk = 0; kk < 2; ++kk)
        a1[i][kk] = *(const bf16x8*)(ab + ((4 + i)*2 + kk) * 1024);
    if (t + 1 < NT) stage_half(B1 + (t+1)*64, (buf^1)*65536 + 49152);
    __builtin_amdgcn_s_setprio(1);
    #pragma unroll
    for (int kk = 0; kk < 2; ++kk)
      #pragma unroll
      for (int i = 0; i < 4; ++i)
        #pragma unroll
        for (int j = 0; j < 2; ++j)
          acc[i][2 + j] = __builtin_amdgcn_mfma_f32_16x16x32_bf16(a0[i][kk], b1[j][kk], acc[i][2 + j], 0, 0, 0);
    __builtin_amdgcn_s_setprio(0);
    asm volatile("s_waitcnt lgkmcnt(0)" ::: "memory");

    // ===== p2: MFMA(a1,b0) quad(1,0); stage Ah0(t+2) =====
    asm volatile("s_barrier" ::: "memory");
    if (t + 2 < NT) stage_half(A0 + (t+2)*64, buf*65536);
    __builtin_amdgcn_s_setprio(1);
    #pragma unroll
    for (int kk = 0; kk < 2; ++kk)
      #pragma unroll
      for (int i = 0; i < 4; ++i)
        #pragma unroll
        for (int j = 0; j < 2; ++j)
          acc[4 + i][j] = __builtin_amdgcn_mfma_f32_16x16x32_bf16(a1[i][kk], b0[j][kk], acc[4 + i][j], 0, 0, 0);
    __builtin_amdgcn_s_setprio(0);

    // ===== p3: MFMA(a1,b1) quad(1,1); vmcnt; read a0',b0'; stage Ah1(t+2) =====
    asm volatile("s_barrier" ::: "memory");
    if (t + 1 < NT) {
      if (t + 2 < NT) asm volatile("s_waitcnt vmcnt(2)" ::: "memory");
      else            asm volatile("s_waitcnt vmcnt(0)" ::: "memory");
      #pragma unroll
      for (int i = 0; i < 4; ++i)
        #pragma unroll
        for (int kk = 0; kk < 2; ++kk)
          a0[i][kk] = *(const bf16x8*)(abn + (i*2 + kk) * 1024);
      #pragma unroll
      for (int j = 0; j < 2; ++j)
        #pragma unroll
        for (int kk = 0; kk < 2; ++kk)
          b0[j][kk] = *(const bf16x8*)(bbn + (j*2 + kk) * 1024);
    }
    if (t + 2 < NT) stage_half(A1 + (t+2)*64, buf*65536 + 16384);
    __builtin_amdgcn_s_setprio(1);
    #pragma unroll
    for (int kk = 0; kk < 2; ++kk)
      #pragma unroll
      for (int i = 0; i < 4; ++i)
        #pragma unroll
        for (int j = 0; j < 2; ++j)
          acc[4 + i][2 + j] = __builtin_amdgcn_mfma_f32_16x16x32_bf16(a1[i][kk], b1[j][kk], acc[4 + i][2 + j], 0, 0, 0);
    __builtin_amdgcn_s_setprio(0);
  }

  // ---- epilogue ----
  #pragma unroll
  for (int i = 0; i < 8; ++i)
    #pragma unroll
    for (int j = 0; j < 4; ++j)
      #pragma unroll
      for (int r = 0; r < 4; ++r) {
        int row = m0 + wm*128 + i*16 + kq*4 + r;
        int col = n0 + wn*64 + j*16 + lrow;
        size_t idx = (size_t)row * N + col;
        float v = acc[i][j][r];
        if (EPI == 0) {
          Cb[idx] = f2bf(v);
        } else if (EPI == 3) {
          Cf[idx] = v;
        } else {
          float g = 0.5f * v * (1.0f + erff(v * 0.70710678118654752f));
          Cb[idx] = f2bf(g);
        }
      }
}

// ---- prep: split heads + per-head exp_map ----
__global__ void prep_qk(const u16* __restrict__ in, const float* __restrict__ headK,
                        u16* __restrict__ Lout, float* __restrict__ l0,
                        int instride, int off) {
  int gid = blockIdx.x * 4 + (threadIdx.x >> 6);
  int lane = threadIdx.x & 63;
  int b = gid >> 15;
  int rem = gid & 32767;
  int h = rem >> 11;
  int s = rem & 2047;
  const u16* src = in + ((size_t)(b * SEQ + s)) * instride + off + h * DHEAD + lane * 2;
  float v0 = bf2f(src[0]), v1 = bf2f(src[1]);
  float nn = v0*v0 + v1*v1;
  #pragma unroll
  for (int m = 1; m < 64; m <<= 1) nn += __shfl_xor(nn, m, 64);
  float Kh = headK[h];
  float sk = sqrtf(-Kh);
  float a = sk * sqrtf(nn);
  float f = (a < 1e-6f) ? (1.0f + a*a*(1.0f/6.0f)) : (sinhf(a) / a);
  u16* dst = Lout + (size_t)gid * DHEAD + lane * 2;
  dst[0] = f2bf(f * v0);
  dst[1] = f2bf(f * v1);
  if (lane == 0) l0[gid] = sqrtf(-1.0f/Kh + f*f*nn);
}

// ---- vtrans ----
__global__ void vtrans(const u16* __restrict__ vb, u16* __restrict__ VT,
                       int instride, int off) {
  __shared__ u16 tile[32][33];
  int bh = blockIdx.x;
  int b = bh >> 4, h = bh & 15;
  int s0 = blockIdx.y * 32, d0 = blockIdx.z * 32;
  int tx = threadIdx.x, ty = threadIdx.y;
  #pragma unroll
  for (int i = 0; i < 4; ++i)
    tile[ty + 8*i][tx] = vb[((size_t)(b*SEQ + s0 + ty + 8*i)) * instride + off + h*DHEAD + d0 + tx];
  __syncthreads();
  #pragma unroll
  for (int i = 0; i < 4; ++i)
    VT[((size_t)bh*DHEAD + d0 + ty + 8*i) * SEQ + s0 + tx] = tile[tx][ty + 8*i];
}

// -------- flash attention v4: LDS double-buffer via gload16, swizzled, raw barriers --------
__global__ __launch_bounds__(256, 2) void attn_kernel(
    const u16* __restrict__ Ql, const u16* __restrict__ Kl,
    const u16* __restrict__ VT, const float* __restrict__ ql0,
    const float* __restrict__ kl0, const float* __restrict__ headK,
    u16* __restrict__ out) {
  __shared__ u16 klds[2][32 * 128];
  __shared__ u16 vlds[2][128 * 32];
  __shared__ u16 plds[4][32 * 36];
  const int tid = threadIdx.x, w = tid >> 6, lane = tid & 63;
  const int lrow = lane & 15, kq = lane >> 4;
  const int id = blockIdx.x;
  const int bh = id & 31;
  const int qb = 15 - (id >> 5);
  const int q0 = qb * 128 + w * 32;
  const int b = bh >> 4, h = bh & 15;
  const float Kh = headK[h];
  const float LOG2E = 1.44269504088896f;
  const float isd = 0.088388347648318447f;
  const float sc_mul = 2.0f * isd * LOG2E;
  const float sc_add = (-2.0f / Kh) * isd * LOG2E;

  const u16* kbase  = Kl + (size_t)bh * SEQ * DHEAD;
  const u16* vtbase = VT + (size_t)bh * DHEAD * SEQ;
  const float* kl0b = kl0 + (size_t)bh * SEQ;
  u16* pw = &plds[w][0];

  bf16x8 aq[2][4];
  const u16* qbase = Ql + ((size_t)bh * SEQ + q0) * DHEAD;
  #pragma unroll
  for (int m = 0; m < 2; ++m)
    #pragma unroll
    for (int dc = 0; dc < 4; ++dc)
      aq[m][dc] = *(const bf16x8*)&qbase[(size_t)(m*16 + lrow) * DHEAD + dc*32 + kq*8];
  float q0r[2][4];
  #pragma unroll
  for (int m = 0; m < 2; ++m)
    #pragma unroll
    for (int r = 0; r < 4; ++r)
      q0r[m][r] = ql0[(size_t)bh * SEQ + q0 + m*16 + kq*4 + r];

  auto stage = [&](int k0, int buf) {
    #pragma unroll
    for (int i = 0; i < 2; ++i) {
      int rl = w*8 + i*4 + (lane >> 4);
      int c = (lane & 15) ^ (rl & 15);
      gload16(kbase + ((size_t)(k0 + rl)) * DHEAD + c * 8,
              &klds[buf][(w*8 + i*4) * 128]);
    }
    #pragma unroll
    for (int i = 0; i < 2; ++i) {
      int rl = w*32 + i*16 + (lane >> 2);
      int c = (lane & 3) ^ ((rl >> 1) & 3);
      gload16(vtbase + (size_t)rl * SEQ + k0 + c * 8,
              &vlds[buf][(w*32 + i*16) * 32]);
    }
  };

  float lacc[2][4] = {};
  f32x4 o[2][8] = {};
  const int niter = qb * 4 + 4;

  stage(0, 0);
  for (int i = 0; i < niter; ++i) {
    const int k0 = i * 32, buf = i & 1;
    float kc0 = kl0b[k0 + lrow];
    float kc1 = kl0b[k0 + 16 + lrow];
    if (i + 1 < niter) {
      stage(k0 + 32, buf ^ 1);
      asm volatile("s_waitcnt vmcnt(4)" ::: "memory");
    } else {
      asm volatile("s_waitcnt vmcnt(0)" ::: "memory");
    }
    asm volatile("s_barrier" ::: "memory");

    f32x4 sc[2][2] = {};
    #pragma unroll
    for (int dc = 0; dc < 4; ++dc) {
      int c = dc*4 + kq;
      bf16x8 bk0 = *(const bf16x8*)&klds[buf][lrow*128        + (c ^ (lrow & 15)) * 8];
      bf16x8 bk1 = *(const bf16x8*)&klds[buf][(16 + lrow)*128 + (c ^ ((16 + lrow) & 15)) * 8];
      #pragma unroll
      for (int m = 0; m < 2; ++m) {
        sc[m][0] = __builtin_amdgcn_mfma_f32_16x16x32_bf16(aq[m][dc], bk0, sc[m][0], 0, 0, 0);
        sc[m][1] = __builtin_amdgcn_mfma_f32_16x16x32_bf16(aq[m][dc], bk1, sc[m][1], 0, 0, 0);
      }
    }
    #pragma unroll
    for (int m = 0; m < 2; ++m)
      #pragma unroll
      for (int r = 0; r < 4; ++r) {
        int qg = q0 + m*16 + kq*4 + r;
        float p0 = exp2f((sc[m][0][r] - q0r[m][r] * kc0) * sc_mul + sc_add);
        float p1 = exp2f((sc[m][1][r] - q0r[m][r] * kc1) * sc_mul + sc_add);
        p0 = (k0 + lrow      <= qg) ? p0 : 0.f;
        p1 = (k0 + 16 + lrow <= qg) ? p1 : 0.f;
        lacc[m][r] += p0 + p1;
        pw[(m*16 + kq*4 + r) * 36 + lrow]      = f2bf(p0);
        pw[(m*16 + kq*4 + r) * 36 + 16 + lrow] = f2bf(p1);
      }
    bf16x8 ap0 = *(const bf16x8*)&pw[(size_t)lrow * 36 + kq*8];
    bf16x8 ap1 = *(const bf16x8*)&pw[(size_t)(16 + lrow) * 36 + kq*8];
    int vc = (kq ^ ((lrow >> 1) & 3)) * 8;
    #pragma unroll
    for (int n = 0; n < 8; ++n) {
      bf16x8 bv = *(const bf16x8*)&vlds[buf][(n*16 + lrow) * 32 + vc];
      o[0][n] = __builtin_amdgcn_mfma_f32_16x16x32_bf16(ap0, bv, o[0][n], 0, 0, 0);
      o[1][n] = __builtin_amdgcn_mfma_f32_16x16x32_bf16(ap1, bv, o[1][n], 0, 0, 0);
    }
    asm volatile("s_barrier" ::: "memory");
  }

  float rcl[2][4];
  #pragma unroll
  for (int m = 0; m < 2; ++m)
    #pragma unroll
    for (int r = 0; r < 4; ++r) {
      float s = lacc[m][r];
      #pragma unroll
      for (int mm = 1; mm < 16; mm <<= 1) s += __shfl_xor(s, mm, 16);
      rcl[m][r] = 1.0f / s;
    }
  #pragma unroll
  for (int m = 0; m < 2; ++m)
    #pragma unroll
    for (int n = 0; n < 8; ++n)
      #pragma unroll
      for (int r = 0; r < 4; ++r) {
        int qg = q0 + m*16 + kq*4 + r;
        out[((size_t)b * SEQ + qg) * DMODEL + h * DHEAD + n*16 + lrow] =
            f2bf(o[m][n][r] * rcl[m][r]);
      }
}

extern "C" void kernel_launch(void* const* d_in, const int* in_sizes, int n_in,
                              void* d_out, int out_size, void* d_ws, size_t ws_size,
                              hipStream_t stream) {
  const float* x      = (const float*)d_in[0];
  const float* scale1 = (const float*)d_in[2];
  const float* scale2 = (const float*)d_in[3];
  const float* Wq     = (const float*)d_in[4];
  const float* Wk     = (const float*)d_in[5];
  const float* Wv     = (const float*)d_in[6];
  const float* Wo     = (const float*)d_in[7];
  const float* headK  = (const float*)d_in[8];
  const float* W1     = (const float*)d_in[9];
  const float* W2     = (const float*)d_in[10];
  float* out = (float*)d_out;

  char* p = (char*)d_ws;
  size_t off = 0;
  auto take = [&](size_t bytes) -> char* {
    char* r = p + off;
    off += (bytes + 255) & ~(size_t)255;
    return r;
  };
  u16* WqT = (u16*)take((size_t)DMODEL*DMODEL*2);   // WqT/WkT/WvT/WoT contiguous 32MB
  u16* WkT = (u16*)take((size_t)DMODEL*DMODEL*2);
  u16* WvT = (u16*)take((size_t)DMODEL*DMODEL*2);
  u16* WoT = (u16*)take((size_t)DMODEL*DMODEL*2);
  u16* W1T = (u16*)take((size_t)DMODEL*DFFN*2);
  u16* W2T = (u16*)take((size_t)DMODEL*DFFN*2);
  float* vres = (float*)take((size_t)MROWS*DMODEL*4);   // v1 -> u2 (in place)
  u16* tbuf = (u16*)take((size_t)MROWS*DMODEL*2);       // t1, attn_out, t2
  u16* qkvb = (u16*)take((size_t)MROWS*3*DMODEL*2);     // fused QKV out (4096 x 6144)
  u16* Qlb  = (u16*)take((size_t)MROWS*DMODEL*2);       // qkvb+Qlb = 64MB contiguous
  u16* Klb  = (u16*)take((size_t)MROWS*DMODEL*2);
  u16* VTb  = (u16*)take((size_t)MROWS*DMODEL*2);
  float* q0b = (float*)take((size_t)NB*NHEAD*SEQ*4);
  float* k0b = (float*)take((size_t)NB*NHEAD*SEQ*4);
  u16* hbuf = qkvb;     // reuse qkvb..Qlb contiguous 64MB = MROWS*DFFN bf16
  u16* attnout = tbuf;  // t1 consumed by QKV gemm before attention writes here

  // K-split partial buffers (scavenged):
  //  - Wo partials: qkvb..Qlb (free after prep_qk/vtrans; consumed by rms_mid3
  //    before W1 overwrites the region as hbuf)
  float* PoA = (float*)qkvb;
  //  - W2 partials: WqT..WoT (32MB, weights dead) + W1T (32MB, dead after W1);
  //    contiguous 64MB so ksel*M*N addressing works.
  float* PfA = (float*)WqT;

  dim3 tb(32, 8);
  transpose_w<<<dim3(DMODEL/32, DMODEL/32), tb, 0, stream>>>(Wq, WqT, DMODEL, DMODEL);
  transpose_w<<<dim3(DMODEL/32, DMODEL/32), tb, 0, stream>>>(Wk, WkT, DMODEL, DMODEL);
  transpose_w<<<dim3(DMODEL/32, DMODEL/32), tb, 0, stream>>>(Wv, WvT, DMODEL, DMODEL);
  transpose_w<<<dim3(DMODEL/32, DMODEL/32), tb, 0, stream>>>(Wo, WoT, DMODEL, DMODEL);
  transpose_w<<<dim3(DFFN/32,   DMODEL/32), tb, 0, stream>>>(W1, W1T, DMODEL, DFFN);
  transpose_w<<<dim3(DMODEL/32, DFFN/32),   tb, 0, stream>>>(W2, W2T, DFFN, DMODEL);

  ln_first<<<MROWS, 256, 0, stream>>>(x, scale1, vres, tbuf);

  // fused QKV: M=4096, N=6144, K=2048 -> 384 blocks, no split
  gemm256<0><<<dim3((3*DMODEL/256)*(MROWS/256), 1), 512, 0, stream>>>(
      tbuf, WqT, qkvb, nullptr, MROWS, 3*DMODEL, DMODEL, DMODEL);

  prep_qk<<<NB*NHEAD*SEQ/4, 256, 0, stream>>>(qkvb, headK, Qlb, q0b, 3*DMODEL, 0);
  prep_qk<<<NB*NHEAD*SEQ/4, 256, 0, stream>>>(qkvb, headK, Klb, k0b, 3*DMODEL, DMODEL);
  vtrans<<<dim3(NB*NHEAD, SEQ/32, DHEAD/32), tb, 0, stream>>>(qkvb, VTb, 3*DMODEL, 2*DMODEL);

  attn_kernel<<<dim3(512), 256, 0, stream>>>(Qlb, Klb, VTb, q0b, k0b, headK, attnout);

  // Wo: M=4096, N=2048, K=2048, K-split 2 -> (128,2) blocks, fp32 partials
  gemm256<3><<<dim3((DMODEL/256)*(MROWS/256), 2), 512, 0, stream>>>(
      attnout, WoT, nullptr, PoA, MROWS, DMODEL, DMODEL, DMODEL/2);

  // u2 = v1 + PoA + PoB (in place) ; t2 = scale2 * u2 / rms
  rms_mid3<<<MROWS, 256, 0, stream>>>(vres, PoA, PoA + (size_t)MROWS*DMODEL, scale2, tbuf);

  // W1 + gelu: M=4096, N=8192, K=2048 -> 512 blocks, no split
  gemm256<2><<<dim3((DFFN/256)*(MROWS/256), 1), 512, 0, stream>>>(
      tbuf, W1T, hbuf, nullptr, MROWS, DFFN, DMODEL, DMODEL);

  // W2: M=4096, N=2048, K=8192, K-split 2 -> (128,2) blocks, fp32 partials
  // into WqT..W1T (contiguous 64MB, both regions dead here)
  gemm256<3><<<dim3((DMODEL/256)*(MROWS/256), 2), 512, 0, stream>>>(
      hbuf, W2T, nullptr, PfA, MROWS, DMODEL, DFFN, DFFN/2);

  final_exp3<<<MROWS, 256, 0, stream>>>(vres, PfA, PfA + (size_t)MROWS*DMODEL, out);

  (void)in_sizes; (void)n_in; (void)out_size; (void)ws_size;
}

// Round 7
// 876.908 us; speedup vs baseline: 1.1578x; 1.0259x over previous
//
#include <hip/hip_runtime.h>
#include <stdint.h>

typedef unsigned short u16;
typedef __attribute__((ext_vector_type(8))) short bf16x8;
typedef __attribute__((ext_vector_type(4))) float f32x4;

#define SEQ    2048
#define NB     2
#define NHEAD  16
#define DHEAD  128
#define DMODEL 2048
#define DFFN   8192
#define MROWS  4096   // NB*SEQ

__device__ __forceinline__ u16 f2bf(float x) {
  union { float f; uint32_t u; } v; v.f = x;
  return (u16)((v.u + 0x7fffu + ((v.u >> 16) & 1u)) >> 16);
}
__device__ __forceinline__ float bf2f(u16 h) {
  union { uint32_t u; float f; } v; v.u = ((uint32_t)h) << 16;
  return v.f;
}
__device__ __forceinline__ void gload16(const void* g, void* l) {
  __builtin_amdgcn_global_load_lds((const __attribute__((address_space(1))) void*)g,
                                   (__attribute__((address_space(3))) void*)l,
                                   16, 0, 0);
}
__device__ __forceinline__ float blockSum256(float v) {
  __shared__ float red[4];
  #pragma unroll
  for (int m = 1; m < 64; m <<= 1) v += __shfl_xor(v, m, 64);
  int w = threadIdx.x >> 6;
  if ((threadIdx.x & 63) == 0) red[w] = v;
  __syncthreads();
  float s = red[0] + red[1] + red[2] + red[3];
  __syncthreads();
  return s;
}

// ---------------- weight transpose fp32 (R,C) -> bf16 (C,R) ----------------
__global__ void transpose_w(const float* __restrict__ in, u16* __restrict__ out, int R, int C) {
  __shared__ float tile[32][33];
  int c0 = blockIdx.x * 32, r0 = blockIdx.y * 32;
  int tx = threadIdx.x, ty = threadIdx.y;
  #pragma unroll
  for (int i = 0; i < 4; ++i)
    tile[ty + 8*i][tx] = in[(size_t)(r0 + ty + 8*i) * C + c0 + tx];
  __syncthreads();
  #pragma unroll
  for (int i = 0; i < 4; ++i)
    out[(size_t)(c0 + ty + 8*i) * R + r0 + tx] = f2bf(tile[tx][ty + 8*i]);
}

// ---- ln_first: x(B,S,2049) -> v1 = log_map(x) fp32, t1 = scale*v1/rms bf16 ----
__global__ void ln_first(const float* __restrict__ x, const float* __restrict__ scale,
                         float* __restrict__ v1, u16* __restrict__ t1) {
  int row = blockIdx.x;
  const float* xr = x + (size_t)row * (DMODEL + 1) + 1;
  float vals[8]; float ss = 0.f;
  #pragma unroll
  for (int i = 0; i < 8; ++i) {
    int idx = threadIdx.x + 256 * i;
    vals[i] = xr[idx];
    ss += vals[i] * vals[i];
  }
  ss = blockSum256(ss);
  float n = sqrtf(ss);
  float f = (n < 1e-6f) ? (1.0f - n * n * (1.0f/6.0f)) : (asinhf(n) / n);
  float rms = sqrtf(f * f * ss * (1.0f / DMODEL) + 1e-6f);
  float ir = 1.0f / rms;
  #pragma unroll
  for (int i = 0; i < 8; ++i) {
    int idx = threadIdx.x + 256 * i;
    float v = f * vals[i];
    v1[(size_t)row * DMODEL + idx] = v;
    t1[(size_t)row * DMODEL + idx] = f2bf(scale[idx] * v * ir);
  }
}

// ---- rms_mid3: u = v + p0 + p1 (write back); t = scale*u/rms(u) ----
__global__ void rms_mid3(float* __restrict__ u, const float* __restrict__ p0,
                         const float* __restrict__ p1, const float* __restrict__ scale,
                         u16* __restrict__ t) {
  int row = blockIdx.x;
  size_t base = (size_t)row * DMODEL;
  float vals[8]; float ss = 0.f;
  #pragma unroll
  for (int i = 0; i < 8; ++i) {
    int idx = threadIdx.x + 256*i;
    float v = u[base + idx] + p0[base + idx] + p1[base + idx];
    vals[i] = v; ss += v*v;
  }
  ss = blockSum256(ss);
  float ir = 1.0f / sqrtf(ss * (1.0f / DMODEL) + 1e-6f);
  #pragma unroll
  for (int i = 0; i < 8; ++i) {
    int idx = threadIdx.x + 256*i;
    u[base + idx] = vals[i];
    t[base + idx] = f2bf(scale[idx]*vals[i]*ir);
  }
}

// ---- final_exp3: out = exp_map_stable(u + p0 + p1), row length 2049 ----
__global__ void final_exp3(const float* __restrict__ u, const float* __restrict__ p0,
                           const float* __restrict__ p1, float* __restrict__ out) {
  int row = blockIdx.x;
  size_t base = (size_t)row * DMODEL;
  float vals[8]; float ss = 0.f;
  #pragma unroll
  for (int i = 0; i < 8; ++i) {
    int idx = threadIdx.x + 256*i;
    float v = u[base + idx] + p0[base + idx] + p1[base + idx];
    vals[i] = v; ss += v*v;
  }
  ss = blockSum256(ss);
  float n = sqrtf(ss);
  float f = (n < 1e-6f) ? (1.0f + n*n*(1.0f/6.0f)) : (sinhf(n)/n);
  float* orow = out + (size_t)row * (DMODEL + 1);
  if (threadIdx.x == 0) orow[0] = sqrtf(1.0f + f*f*ss);
  #pragma unroll
  for (int i = 0; i < 8; ++i) { int idx = threadIdx.x + 256*i; orow[1+idx] = f*vals[i]; }
}

// ============================================================================
// GEMM 256x256 tile, BK=64, 8 waves (2M x 4N), read-ahead pipelined phases,
// BOTH A and B prefetched 2 K-tiles deep. Per tile t (buf = t&1):
//   p0: bar | read b1[t]              | MFMA q00(a0,b0)
//   p1: bar | read a1[t]              | MFMA q01(a0,b1) | lgkmcnt(0)
//   p2: bar | stage Ah0,Bh0(t+2)->buf | MFMA q10(a1,b0) | vmcnt(4)
//   p3: bar | read a0',b0'(t+1,buf^1) | stage Ah1,Bh1(t+2)->buf | MFMA q11
// Safety: p1-end lgkmcnt(0) + p2 barrier => all waves' reads of buf drained
// before p2/p3 overwrite it. p2-end vmcnt(4) BEFORE p3's barrier => every
// wave's t+1 stages drained at the barrier => p3's reads cross-wave safe.
// Tails: vmcnt(0) when t+2>=NT; reads guarded by t+1<NT.
// st_16x32 swizzle both-sides (T2), setprio (T5), XCD swizzle (T1).
// K-split: blockIdx.y selects K-half; EPI 3 writes fp32 partials at +y*M*N.
// EPI 0: bf16 store; EPI 2: gelu -> bf16.
// ============================================================================
template<int EPI>
__global__ __launch_bounds__(512, 2) void gemm256(
    const u16* __restrict__ A, const u16* __restrict__ Bt,
    u16* __restrict__ Cb, float* Cf,
    int M, int N, int K, int kHalf)
{
  __shared__ __attribute__((aligned(128))) char smem[131072];
  const int tid = threadIdx.x;
  const int w = tid >> 6, lane = tid & 63;
  const int lrow = lane & 15, kq = lane >> 4;
  const int wm = w >> 2, wn = w & 3;

  // K-split select
  const int ksel = blockIdx.y;
  A  += (size_t)ksel * kHalf;
  Bt += (size_t)ksel * kHalf;
  if (EPI == 3) Cf += (size_t)ksel * M * N;
  const int NT = kHalf >> 6;      // K-tiles in this split (>= 16 for all uses)

  // T1: XCD-aware bijective swizzle (gridDim.x is a multiple of 8)
  const int nwg = gridDim.x;
  const int cpx = nwg >> 3;
  const int sid = (blockIdx.x & 7) * cpx + (blockIdx.x >> 3);
  const int NX = N >> 8;
  const int bx = sid % NX, by = sid / NX;
  const int m0 = by * 256, n0 = bx * 256;

  // inverse-swizzled global source offsets for the 2 staging rounds
  size_t goff[2];
  #pragma unroll
  for (int r = 0; r < 2; ++r) {
    int L = r * 8192 + tid * 16;                  // linear LDS byte this thread fills
    int U = L ^ (((L >> 9) & 1) << 5);            // unswizzled byte offset in half
    int si = U >> 10;
    int row = (si >> 1) * 16 + ((U >> 6) & 15);
    int col = (si & 1) * 32 + ((U & 63) >> 1);
    goff[r] = (size_t)row * K + col;
  }
  auto stage_half = [&](const u16* g, int ldsOff) {
    #pragma unroll
    for (int r = 0; r < 2; ++r)
      gload16(g + goff[r], smem + ldsOff + r * 8192 + w * 1024);
  };

  const u16* A0 = A  + (size_t)m0 * K;
  const u16* A1 = A  + (size_t)(m0 + 128) * K;
  const u16* B0 = Bt + (size_t)n0 * K;
  const u16* B1 = Bt + (size_t)(n0 + 128) * K;

  // swizzled per-lane fragment byte offset within a half
  const int aoff = (lrow * 64 + kq * 16) ^ ((lrow & 8) << 2);

  f32x4 acc[8][4] = {};
  bf16x8 a0[4][2], a1[4][2], b0[2][2], b1[2][2];

  // ---- prologue: stage tile0 -> buf0, tile1 -> buf1; drain tile0; read a0,b0 ----
  stage_half(A0,       0);
  stage_half(A1,       16384);
  stage_half(B0,       32768);
  stage_half(B1,       49152);
  stage_half(A0 + 64,  65536);
  stage_half(A1 + 64,  65536 + 16384);
  stage_half(B0 + 64,  65536 + 32768);
  stage_half(B1 + 64,  65536 + 49152);
  asm volatile("s_waitcnt vmcnt(8)" ::: "memory");   // own tile-0 stages done
  asm volatile("s_barrier" ::: "memory");            // -> all waves' tile-0 visible
  {
    const char* ab = smem + wm * 16384 + aoff;
    const char* bb = smem + 32768 + (wn >> 1) * 16384 + (wn & 1) * 8192 + aoff;
    #pragma unroll
    for (int i = 0; i < 4; ++i)
      #pragma unroll
      for (int kk = 0; kk < 2; ++kk)
        a0[i][kk] = *(const bf16x8*)(ab + (i*2 + kk) * 1024);
    #pragma unroll
    for (int j = 0; j < 2; ++j)
      #pragma unroll
      for (int kk = 0; kk < 2; ++kk)
        b0[j][kk] = *(const bf16x8*)(bb + (j*2 + kk) * 1024);
  }

  for (int t = 0; t < NT; ++t) {
    const int buf = t & 1;
    const char* ab  = smem + buf * 65536 + wm * 16384 + aoff;
    const char* bb  = smem + buf * 65536 + 32768 + (wn >> 1) * 16384 + (wn & 1) * 8192 + aoff;
    const char* abn = smem + (buf^1) * 65536 + wm * 16384 + aoff;
    const char* bbn = smem + (buf^1) * 65536 + 32768 + (wn >> 1) * 16384 + (wn & 1) * 8192 + aoff;

    // ===== p0: read b1[t]; MFMA q00(a0,b0) =====
    asm volatile("s_barrier" ::: "memory");
    #pragma unroll
    for (int j = 0; j < 2; ++j)
      #pragma unroll
      for (int kk = 0; kk < 2; ++kk)
        b1[j][kk] = *(const bf16x8*)(bb + ((2 + j)*2 + kk) * 1024);
    __builtin_amdgcn_s_setprio(1);
    #pragma unroll
    for (int kk = 0; kk < 2; ++kk)
      #pragma unroll
      for (int i = 0; i < 4; ++i)
        #pragma unroll
        for (int j = 0; j < 2; ++j)
          acc[i][j] = __builtin_amdgcn_mfma_f32_16x16x32_bf16(a0[i][kk], b0[j][kk], acc[i][j], 0, 0, 0);
    __builtin_amdgcn_s_setprio(0);

    // ===== p1: read a1[t]; MFMA q01(a0,b1); drain lgkm (buf now dead) =====
    asm volatile("s_barrier" ::: "memory");
    #pragma unroll
    for (int i = 0; i < 4; ++i)
      #pragma unroll
      for (int kk = 0; kk < 2; ++kk)
        a1[i][kk] = *(const bf16x8*)(ab + ((4 + i)*2 + kk) * 1024);
    __builtin_amdgcn_s_setprio(1);
    #pragma unroll
    for (int kk = 0; kk < 2; ++kk)
      #pragma unroll
      for (int i = 0; i < 4; ++i)
        #pragma unroll
        for (int j = 0; j < 2; ++j)
          acc[i][2 + j] = __builtin_amdgcn_mfma_f32_16x16x32_bf16(a0[i][kk], b1[j][kk], acc[i][2 + j], 0, 0, 0);
    __builtin_amdgcn_s_setprio(0);
    asm volatile("s_waitcnt lgkmcnt(0)" ::: "memory");

    // ===== p2: stage Ah0,Bh0(t+2)->buf; MFMA q10(a1,b0); vmcnt =====
    asm volatile("s_barrier" ::: "memory");
    if (t + 2 < NT) {
      stage_half(A0 + (t+2)*64, buf*65536);
      stage_half(B0 + (t+2)*64, buf*65536 + 32768);
    }
    __builtin_amdgcn_s_setprio(1);
    #pragma unroll
    for (int kk = 0; kk < 2; ++kk)
      #pragma unroll
      for (int i = 0; i < 4; ++i)
        #pragma unroll
        for (int j = 0; j < 2; ++j)
          acc[4 + i][j] = __builtin_amdgcn_mfma_f32_16x16x32_bf16(a1[i][kk], b0[j][kk], acc[4 + i][j], 0, 0, 0);
    __builtin_amdgcn_s_setprio(0);
    if (t + 2 < NT) asm volatile("s_waitcnt vmcnt(4)" ::: "memory");
    else            asm volatile("s_waitcnt vmcnt(0)" ::: "memory");

    // ===== p3: read a0',b0'(t+1); stage Ah1,Bh1(t+2)->buf; MFMA q11(a1,b1) =====
    asm volatile("s_barrier" ::: "memory");
    if (t + 1 < NT) {
      #pragma unroll
      for (int i = 0; i < 4; ++i)
        #pragma unroll
        for (int kk = 0; kk < 2; ++kk)
          a0[i][kk] = *(const bf16x8*)(abn + (i*2 + kk) * 1024);
      #pragma unroll
      for (int j = 0; j < 2; ++j)
        #pragma unroll
        for (int kk = 0; kk < 2; ++kk)
          b0[j][kk] = *(const bf16x8*)(bbn + (j*2 + kk) * 1024);
    }
    if (t + 2 < NT) {
      stage_half(A1 + (t+2)*64, buf*65536 + 16384);
      stage_half(B1 + (t+2)*64, buf*65536 + 49152);
    }
    __builtin_amdgcn_s_setprio(1);
    #pragma unroll
    for (int kk = 0; kk < 2; ++kk)
      #pragma unroll
      for (int i = 0; i < 4; ++i)
        #pragma unroll
        for (int j = 0; j < 2; ++j)
          acc[4 + i][2 + j] = __builtin_amdgcn_mfma_f32_16x16x32_bf16(a1[i][kk], b1[j][kk], acc[4 + i][2 + j], 0, 0, 0);
    __builtin_amdgcn_s_setprio(0);
  }

  // ---- epilogue ----
  #pragma unroll
  for (int i = 0; i < 8; ++i)
    #pragma unroll
    for (int j = 0; j < 4; ++j)
      #pragma unroll
      for (int r = 0; r < 4; ++r) {
        int row = m0 + wm*128 + i*16 + kq*4 + r;
        int col = n0 + wn*64 + j*16 + lrow;
        size_t idx = (size_t)row * N + col;
        float v = acc[i][j][r];
        if (EPI == 0) {
          Cb[idx] = f2bf(v);
        } else if (EPI == 3) {
          Cf[idx] = v;
        } else {
          float g = 0.5f * v * (1.0f + erff(v * 0.70710678118654752f));
          Cb[idx] = f2bf(g);
        }
      }
}

// ---- prep: split heads + per-head exp_map ----
__global__ void prep_qk(const u16* __restrict__ in, const float* __restrict__ headK,
                        u16* __restrict__ Lout, float* __restrict__ l0,
                        int instride, int off) {
  int gid = blockIdx.x * 4 + (threadIdx.x >> 6);
  int lane = threadIdx.x & 63;
  int b = gid >> 15;
  int rem = gid & 32767;
  int h = rem >> 11;
  int s = rem & 2047;
  const u16* src = in + ((size_t)(b * SEQ + s)) * instride + off + h * DHEAD + lane * 2;
  float v0 = bf2f(src[0]), v1 = bf2f(src[1]);
  float nn = v0*v0 + v1*v1;
  #pragma unroll
  for (int m = 1; m < 64; m <<= 1) nn += __shfl_xor(nn, m, 64);
  float Kh = headK[h];
  float sk = sqrtf(-Kh);
  float a = sk * sqrtf(nn);
  float f = (a < 1e-6f) ? (1.0f + a*a*(1.0f/6.0f)) : (sinhf(a) / a);
  u16* dst = Lout + (size_t)gid * DHEAD + lane * 2;
  dst[0] = f2bf(f * v0);
  dst[1] = f2bf(f * v1);
  if (lane == 0) l0[gid] = sqrtf(-1.0f/Kh + f*f*nn);
}

// ---- vtrans ----
__global__ void vtrans(const u16* __restrict__ vb, u16* __restrict__ VT,
                       int instride, int off) {
  __shared__ u16 tile[32][33];
  int bh = blockIdx.x;
  int b = bh >> 4, h = bh & 15;
  int s0 = blockIdx.y * 32, d0 = blockIdx.z * 32;
  int tx = threadIdx.x, ty = threadIdx.y;
  #pragma unroll
  for (int i = 0; i < 4; ++i)
    tile[ty + 8*i][tx] = vb[((size_t)(b*SEQ + s0 + ty + 8*i)) * instride + off + h*DHEAD + d0 + tx];
  __syncthreads();
  #pragma unroll
  for (int i = 0; i < 4; ++i)
    VT[((size_t)bh*DHEAD + d0 + ty + 8*i) * SEQ + s0 + tx] = tile[tx][ty + 8*i];
}

// -------- flash attention v4: LDS double-buffer via gload16, swizzled, raw barriers --------
__global__ __launch_bounds__(256, 2) void attn_kernel(
    const u16* __restrict__ Ql, const u16* __restrict__ Kl,
    const u16* __restrict__ VT, const float* __restrict__ ql0,
    const float* __restrict__ kl0, const float* __restrict__ headK,
    u16* __restrict__ out) {
  __shared__ u16 klds[2][32 * 128];
  __shared__ u16 vlds[2][128 * 32];
  __shared__ u16 plds[4][32 * 36];
  const int tid = threadIdx.x, w = tid >> 6, lane = tid & 63;
  const int lrow = lane & 15, kq = lane >> 4;
  const int id = blockIdx.x;
  const int bh = id & 31;
  const int qb = 15 - (id >> 5);
  const int q0 = qb * 128 + w * 32;
  const int b = bh >> 4, h = bh & 15;
  const float Kh = headK[h];
  const float LOG2E = 1.44269504088896f;
  const float isd = 0.088388347648318447f;
  const float sc_mul = 2.0f * isd * LOG2E;
  const float sc_add = (-2.0f / Kh) * isd * LOG2E;

  const u16* kbase  = Kl + (size_t)bh * SEQ * DHEAD;
  const u16* vtbase = VT + (size_t)bh * DHEAD * SEQ;
  const float* kl0b = kl0 + (size_t)bh * SEQ;
  u16* pw = &plds[w][0];

  bf16x8 aq[2][4];
  const u16* qbase = Ql + ((size_t)bh * SEQ + q0) * DHEAD;
  #pragma unroll
  for (int m = 0; m < 2; ++m)
    #pragma unroll
    for (int dc = 0; dc < 4; ++dc)
      aq[m][dc] = *(const bf16x8*)&qbase[(size_t)(m*16 + lrow) * DHEAD + dc*32 + kq*8];
  float q0r[2][4];
  #pragma unroll
  for (int m = 0; m < 2; ++m)
    #pragma unroll
    for (int r = 0; r < 4; ++r)
      q0r[m][r] = ql0[(size_t)bh * SEQ + q0 + m*16 + kq*4 + r];

  auto stage = [&](int k0, int buf) {
    #pragma unroll
    for (int i = 0; i < 2; ++i) {
      int rl = w*8 + i*4 + (lane >> 4);
      int c = (lane & 15) ^ (rl & 15);
      gload16(kbase + ((size_t)(k0 + rl)) * DHEAD + c * 8,
              &klds[buf][(w*8 + i*4) * 128]);
    }
    #pragma unroll
    for (int i = 0; i < 2; ++i) {
      int rl = w*32 + i*16 + (lane >> 2);
      int c = (lane & 3) ^ ((rl >> 1) & 3);
      gload16(vtbase + (size_t)rl * SEQ + k0 + c * 8,
              &vlds[buf][(w*32 + i*16) * 32]);
    }
  };

  float lacc[2][4] = {};
  f32x4 o[2][8] = {};
  const int niter = qb * 4 + 4;

  stage(0, 0);
  for (int i = 0; i < niter; ++i) {
    const int k0 = i * 32, buf = i & 1;
    float kc0 = kl0b[k0 + lrow];
    float kc1 = kl0b[k0 + 16 + lrow];
    if (i + 1 < niter) {
      stage(k0 + 32, buf ^ 1);
      asm volatile("s_waitcnt vmcnt(4)" ::: "memory");
    } else {
      asm volatile("s_waitcnt vmcnt(0)" ::: "memory");
    }
    asm volatile("s_barrier" ::: "memory");

    f32x4 sc[2][2] = {};
    #pragma unroll
    for (int dc = 0; dc < 4; ++dc) {
      int c = dc*4 + kq;
      bf16x8 bk0 = *(const bf16x8*)&klds[buf][lrow*128        + (c ^ (lrow & 15)) * 8];
      bf16x8 bk1 = *(const bf16x8*)&klds[buf][(16 + lrow)*128 + (c ^ ((16 + lrow) & 15)) * 8];
      #pragma unroll
      for (int m = 0; m < 2; ++m) {
        sc[m][0] = __builtin_amdgcn_mfma_f32_16x16x32_bf16(aq[m][dc], bk0, sc[m][0], 0, 0, 0);
        sc[m][1] = __builtin_amdgcn_mfma_f32_16x16x32_bf16(aq[m][dc], bk1, sc[m][1], 0, 0, 0);
      }
    }
    #pragma unroll
    for (int m = 0; m < 2; ++m)
      #pragma unroll
      for (int r = 0; r < 4; ++r) {
        int qg = q0 + m*16 + kq*4 + r;
        float p0 = exp2f((sc[m][0][r] - q0r[m][r] * kc0) * sc_mul + sc_add);
        float p1 = exp2f((sc[m][1][r] - q0r[m][r] * kc1) * sc_mul + sc_add);
        p0 = (k0 + lrow      <= qg) ? p0 : 0.f;
        p1 = (k0 + 16 + lrow <= qg) ? p1 : 0.f;
        lacc[m][r] += p0 + p1;
        pw[(m*16 + kq*4 + r) * 36 + lrow]      = f2bf(p0);
        pw[(m*16 + kq*4 + r) * 36 + 16 + lrow] = f2bf(p1);
      }
    bf16x8 ap0 = *(const bf16x8*)&pw[(size_t)lrow * 36 + kq*8];
    bf16x8 ap1 = *(const bf16x8*)&pw[(size_t)(16 + lrow) * 36 + kq*8];
    int vc = (kq ^ ((lrow >> 1) & 3)) * 8;
    #pragma unroll
    for (int n = 0; n < 8; ++n) {
      bf16x8 bv = *(const bf16x8*)&vlds[buf][(n*16 + lrow) * 32 + vc];
      o[0][n] = __builtin_amdgcn_mfma_f32_16x16x32_bf16(ap0, bv, o[0][n], 0, 0, 0);
      o[1][n] = __builtin_amdgcn_mfma_f32_16x16x32_bf16(ap1, bv, o[1][n], 0, 0, 0);
    }
    asm volatile("s_barrier" ::: "memory");
  }

  float rcl[2][4];
  #pragma unroll
  for (int m = 0; m < 2; ++m)
    #pragma unroll
    for (int r = 0; r < 4; ++r) {
      float s = lacc[m][r];
      #pragma unroll
      for (int mm = 1; mm < 16; mm <<= 1) s += __shfl_xor(s, mm, 16);
      rcl[m][r] = 1.0f / s;
    }
  #pragma unroll
  for (int m = 0; m < 2; ++m)
    #pragma unroll
    for (int n = 0; n < 8; ++n)
      #pragma unroll
      for (int r = 0; r < 4; ++r) {
        int qg = q0 + m*16 + kq*4 + r;
        out[((size_t)b * SEQ + qg) * DMODEL + h * DHEAD + n*16 + lrow] =
            f2bf(o[m][n][r] * rcl[m][r]);
      }
}

extern "C" void kernel_launch(void* const* d_in, const int* in_sizes, int n_in,
                              void* d_out, int out_size, void* d_ws, size_t ws_size,
                              hipStream_t stream) {
  const float* x      = (const float*)d_in[0];
  const float* scale1 = (const float*)d_in[2];
  const float* scale2 = (const float*)d_in[3];
  const float* Wq     = (const float*)d_in[4];
  const float* Wk     = (const float*)d_in[5];
  const float* Wv     = (const float*)d_in[6];
  const float* Wo     = (const float*)d_in[7];
  const float* headK  = (const float*)d_in[8];
  const float* W1     = (const float*)d_in[9];
  const float* W2     = (const float*)d_in[10];
  float* out = (float*)d_out;

  char* p = (char*)d_ws;
  size_t off = 0;
  auto take = [&](size_t bytes) -> char* {
    char* r = p + off;
    off += (bytes + 255) & ~(size_t)255;
    return r;
  };
  u16* WqT = (u16*)take((size_t)DMODEL*DMODEL*2);   // WqT/WkT/WvT/WoT contiguous 32MB
  u16* WkT = (u16*)take((size_t)DMODEL*DMODEL*2);
  u16* WvT = (u16*)take((size_t)DMODEL*DMODEL*2);
  u16* WoT = (u16*)take((size_t)DMODEL*DMODEL*2);
  u16* W1T = (u16*)take((size_t)DMODEL*DFFN*2);
  u16* W2T = (u16*)take((size_t)DMODEL*DFFN*2);
  float* vres = (float*)take((size_t)MROWS*DMODEL*4);   // v1 -> u2 (in place)
  u16* tbuf = (u16*)take((size_t)MROWS*DMODEL*2);       // t1, attn_out, t2
  u16* qkvb = (u16*)take((size_t)MROWS*3*DMODEL*2);     // fused QKV out (4096 x 6144)
  u16* Qlb  = (u16*)take((size_t)MROWS*DMODEL*2);       // qkvb+Qlb = 64MB contiguous
  u16* Klb  = (u16*)take((size_t)MROWS*DMODEL*2);
  u16* VTb  = (u16*)take((size_t)MROWS*DMODEL*2);
  float* q0b = (float*)take((size_t)NB*NHEAD*SEQ*4);
  float* k0b = (float*)take((size_t)NB*NHEAD*SEQ*4);
  u16* hbuf = qkvb;     // reuse qkvb..Qlb contiguous 64MB = MROWS*DFFN bf16
  u16* attnout = tbuf;  // t1 consumed by QKV gemm before attention writes here

  // K-split partial buffers (scavenged):
  //  - Wo partials: qkvb..Qlb (free after prep_qk/vtrans; consumed by rms_mid3
  //    before W1 overwrites the region as hbuf)
  float* PoA = (float*)qkvb;
  //  - W2 partials: WqT..WoT (32MB, weights dead) + W1T (32MB, dead after W1);
  //    contiguous 64MB so ksel*M*N addressing works.
  float* PfA = (float*)WqT;

  dim3 tb(32, 8);
  transpose_w<<<dim3(DMODEL/32, DMODEL/32), tb, 0, stream>>>(Wq, WqT, DMODEL, DMODEL);
  transpose_w<<<dim3(DMODEL/32, DMODEL/32), tb, 0, stream>>>(Wk, WkT, DMODEL, DMODEL);
  transpose_w<<<dim3(DMODEL/32, DMODEL/32), tb, 0, stream>>>(Wv, WvT, DMODEL, DMODEL);
  transpose_w<<<dim3(DMODEL/32, DMODEL/32), tb, 0, stream>>>(Wo, WoT, DMODEL, DMODEL);
  transpose_w<<<dim3(DFFN/32,   DMODEL/32), tb, 0, stream>>>(W1, W1T, DMODEL, DFFN);
  transpose_w<<<dim3(DMODEL/32, DFFN/32),   tb, 0, stream>>>(W2, W2T, DFFN, DMODEL);

  ln_first<<<MROWS, 256, 0, stream>>>(x, scale1, vres, tbuf);

  // fused QKV: M=4096, N=6144, K=2048 -> 384 blocks, no split
  gemm256<0><<<dim3((3*DMODEL/256)*(MROWS/256), 1), 512, 0, stream>>>(
      tbuf, WqT, qkvb, nullptr, MROWS, 3*DMODEL, DMODEL, DMODEL);

  prep_qk<<<NB*NHEAD*SEQ/4, 256, 0, stream>>>(qkvb, headK, Qlb, q0b, 3*DMODEL, 0);
  prep_qk<<<NB*NHEAD*SEQ/4, 256, 0, stream>>>(qkvb, headK, Klb, k0b, 3*DMODEL, DMODEL);
  vtrans<<<dim3(NB*NHEAD, SEQ/32, DHEAD/32), tb, 0, stream>>>(qkvb, VTb, 3*DMODEL, 2*DMODEL);

  attn_kernel<<<dim3(512), 256, 0, stream>>>(Qlb, Klb, VTb, q0b, k0b, headK, attnout);

  // Wo: M=4096, N=2048, K=2048, K-split 2 -> (128,2) blocks, fp32 partials
  gemm256<3><<<dim3((DMODEL/256)*(MROWS/256), 2), 512, 0, stream>>>(
      attnout, WoT, nullptr, PoA, MROWS, DMODEL, DMODEL, DMODEL/2);

  // u2 = v1 + PoA + PoB (in place) ; t2 = scale2 * u2 / rms
  rms_mid3<<<MROWS, 256, 0, stream>>>(vres, PoA, PoA + (size_t)MROWS*DMODEL, scale2, tbuf);

  // W1 + gelu: M=4096, N=8192, K=2048 -> 512 blocks, no split
  gemm256<2><<<dim3((DFFN/256)*(MROWS/256), 1), 512, 0, stream>>>(
      tbuf, W1T, hbuf, nullptr, MROWS, DFFN, DMODEL, DMODEL);

  // W2: M=4096, N=2048, K=8192, K-split 2 -> (128,2) blocks, fp32 partials
  // into WqT..W1T (contiguous 64MB, both regions dead here)
  gemm256<3><<<dim3((DMODEL/256)*(MROWS/256), 2), 512, 0, stream>>>(
      hbuf, W2T, nullptr, PfA, MROWS, DMODEL, DFFN, DFFN/2);

  final_exp3<<<MROWS, 256, 0, stream>>>(vres, PfA, PfA + (size_t)MROWS*DMODEL, out);

  (void)in_sizes; (void)n_in; (void)out_size; (void)ws_size;
}

// Round 8
// 868.923 us; speedup vs baseline: 1.1685x; 1.0092x over previous
//
#include <hip/hip_runtime.h>
#include <stdint.h>

typedef unsigned short u16;
typedef __attribute__((ext_vector_type(8))) short bf16x8;
typedef __attribute__((ext_vector_type(4))) float f32x4;

#define SEQ    2048
#define NB     2
#define NHEAD  16
#define DHEAD  128
#define DMODEL 2048
#define DFFN   8192
#define MROWS  4096   // NB*SEQ

__device__ __forceinline__ u16 f2bf(float x) {
  union { float f; uint32_t u; } v; v.f = x;
  return (u16)((v.u + 0x7fffu + ((v.u >> 16) & 1u)) >> 16);
}
__device__ __forceinline__ float bf2f(u16 h) {
  union { uint32_t u; float f; } v; v.u = ((uint32_t)h) << 16;
  return v.f;
}
__device__ __forceinline__ void gload16(const void* g, void* l) {
  __builtin_amdgcn_global_load_lds((const __attribute__((address_space(1))) void*)g,
                                   (__attribute__((address_space(3))) void*)l,
                                   16, 0, 0);
}
__device__ __forceinline__ float blockSum256(float v) {
  __shared__ float red[4];
  #pragma unroll
  for (int m = 1; m < 64; m <<= 1) v += __shfl_xor(v, m, 64);
  int w = threadIdx.x >> 6;
  if ((threadIdx.x & 63) == 0) red[w] = v;
  __syncthreads();
  float s = red[0] + red[1] + red[2] + red[3];
  __syncthreads();
  return s;
}

// ---------------- weight transpose fp32 (R,C) -> bf16 (C,R) ----------------
__global__ void transpose_w(const float* __restrict__ in, u16* __restrict__ out, int R, int C) {
  __shared__ float tile[32][33];
  int c0 = blockIdx.x * 32, r0 = blockIdx.y * 32;
  int tx = threadIdx.x, ty = threadIdx.y;
  #pragma unroll
  for (int i = 0; i < 4; ++i)
    tile[ty + 8*i][tx] = in[(size_t)(r0 + ty + 8*i) * C + c0 + tx];
  __syncthreads();
  #pragma unroll
  for (int i = 0; i < 4; ++i)
    out[(size_t)(c0 + ty + 8*i) * R + r0 + tx] = f2bf(tile[tx][ty + 8*i]);
}

// ---- ln_first: x(B,S,2049) -> v1 = log_map(x) fp32, t1 = scale*v1/rms bf16 ----
__global__ void ln_first(const float* __restrict__ x, const float* __restrict__ scale,
                         float* __restrict__ v1, u16* __restrict__ t1) {
  int row = blockIdx.x;
  const float* xr = x + (size_t)row * (DMODEL + 1) + 1;
  float vals[8]; float ss = 0.f;
  #pragma unroll
  for (int i = 0; i < 8; ++i) {
    int idx = threadIdx.x + 256 * i;
    vals[i] = xr[idx];
    ss += vals[i] * vals[i];
  }
  ss = blockSum256(ss);
  float n = sqrtf(ss);
  float f = (n < 1e-6f) ? (1.0f - n * n * (1.0f/6.0f)) : (asinhf(n) / n);
  float rms = sqrtf(f * f * ss * (1.0f / DMODEL) + 1e-6f);
  float ir = 1.0f / rms;
  #pragma unroll
  for (int i = 0; i < 8; ++i) {
    int idx = threadIdx.x + 256 * i;
    float v = f * vals[i];
    v1[(size_t)row * DMODEL + idx] = v;
    t1[(size_t)row * DMODEL + idx] = f2bf(scale[idx] * v * ir);
  }
}

// ---- rms_mid3: u = v + p0 + p1 (write back); t = scale*u/rms(u) ----
__global__ void rms_mid3(float* __restrict__ u, const float* __restrict__ p0,
                         const float* __restrict__ p1, const float* __restrict__ scale,
                         u16* __restrict__ t) {
  int row = blockIdx.x;
  size_t base = (size_t)row * DMODEL;
  float vals[8]; float ss = 0.f;
  #pragma unroll
  for (int i = 0; i < 8; ++i) {
    int idx = threadIdx.x + 256*i;
    float v = u[base + idx] + p0[base + idx] + p1[base + idx];
    vals[i] = v; ss += v*v;
  }
  ss = blockSum256(ss);
  float ir = 1.0f / sqrtf(ss * (1.0f / DMODEL) + 1e-6f);
  #pragma unroll
  for (int i = 0; i < 8; ++i) {
    int idx = threadIdx.x + 256*i;
    u[base + idx] = vals[i];
    t[base + idx] = f2bf(scale[idx]*vals[i]*ir);
  }
}

// ---- final_exp3: out = exp_map_stable(u + p0 + p1), row length 2049 ----
__global__ void final_exp3(const float* __restrict__ u, const float* __restrict__ p0,
                           const float* __restrict__ p1, float* __restrict__ out) {
  int row = blockIdx.x;
  size_t base = (size_t)row * DMODEL;
  float vals[8]; float ss = 0.f;
  #pragma unroll
  for (int i = 0; i < 8; ++i) {
    int idx = threadIdx.x + 256*i;
    float v = u[base + idx] + p0[base + idx] + p1[base + idx];
    vals[i] = v; ss += v*v;
  }
  ss = blockSum256(ss);
  float n = sqrtf(ss);
  float f = (n < 1e-6f) ? (1.0f + n*n*(1.0f/6.0f)) : (sinhf(n)/n);
  float* orow = out + (size_t)row * (DMODEL + 1);
  if (threadIdx.x == 0) orow[0] = sqrtf(1.0f + f*f*ss);
  #pragma unroll
  for (int i = 0; i < 8; ++i) { int idx = threadIdx.x + 256*i; orow[1+idx] = f*vals[i]; }
}

// ============================================================================
// GEMM 256x256 tile, BK=64, 8 waves (2M x 4N). LDS-read-balanced pipelined
// schedule: per-wave ds_reads spread 8/4/8/4 across the 4 phases (was 4/8/0/12)
// so the per-phase CU LDS service (~768/384 cyc) overlaps the 515-cyc MFMA
// bursts instead of spiking to 1150 in one phase. 2-K-tile-deep prefetch.
// Per tile t (buf = t&1, nbuf holds t+1):
//   p0: bar | read a1[0..1],b1 (8, buf)  | MFMA q00(a0,b0)
//   p1: bar | read a1[2..3]   (4, buf)  | MFMA q01(a0,b1) | lgkmcnt(0)
//       | vmcnt(4)  [drains prior-p2 = A-halves(t+1)]
//   p2: bar | read a0'(t+1)   (8, nbuf) | stage Ah0,Ah1(t+2)->buf
//       | MFMA q10(a1,b0) | vmcnt(4|0) [drains prior-p3 = B-halves(t+1)]
//   p3: bar | read b0'(t+1)   (4, nbuf) | stage Bh0,Bh1(t+2)->buf
//       | MFMA q11(a1,b1)
// Safety: p1-end lgkmcnt(0) + p2 barrier => all waves' buf reads drained before
// any wave stages into buf. Each vmcnt precedes the barrier that precedes the
// dependent reads => cross-wave visibility guaranteed. In-order lgkm drain
// covers a0'/b0' (read >=1 phase before use). Tails: waits degrade to vmcnt(0),
// reads/stages guarded by t+1/t+2 < NT.
// st_16x32 swizzle both-sides (T2), setprio (T5), XCD swizzle (T1).
// K-split: blockIdx.y selects K-half; EPI 3 writes fp32 partials at +y*M*N.
// EPI 0: bf16 store; EPI 2: gelu -> bf16.
// ============================================================================
template<int EPI>
__global__ __launch_bounds__(512, 2) void gemm256(
    const u16* __restrict__ A, const u16* __restrict__ Bt,
    u16* __restrict__ Cb, float* Cf,
    int M, int N, int K, int kHalf)
{
  __shared__ __attribute__((aligned(128))) char smem[131072];
  const int tid = threadIdx.x;
  const int w = tid >> 6, lane = tid & 63;
  const int lrow = lane & 15, kq = lane >> 4;
  const int wm = w >> 2, wn = w & 3;

  // K-split select
  const int ksel = blockIdx.y;
  A  += (size_t)ksel * kHalf;
  Bt += (size_t)ksel * kHalf;
  if (EPI == 3) Cf += (size_t)ksel * M * N;
  const int NT = kHalf >> 6;      // K-tiles in this split (>= 16 for all uses)

  // T1: XCD-aware bijective swizzle (gridDim.x is a multiple of 8)
  const int nwg = gridDim.x;
  const int cpx = nwg >> 3;
  const int sid = (blockIdx.x & 7) * cpx + (blockIdx.x >> 3);
  const int NX = N >> 8;
  const int bx = sid % NX, by = sid / NX;
  const int m0 = by * 256, n0 = bx * 256;

  // inverse-swizzled global source offsets for the 2 staging rounds
  size_t goff[2];
  #pragma unroll
  for (int r = 0; r < 2; ++r) {
    int L = r * 8192 + tid * 16;                  // linear LDS byte this thread fills
    int U = L ^ (((L >> 9) & 1) << 5);            // unswizzled byte offset in half
    int si = U >> 10;
    int row = (si >> 1) * 16 + ((U >> 6) & 15);
    int col = (si & 1) * 32 + ((U & 63) >> 1);
    goff[r] = (size_t)row * K + col;
  }
  auto stage_half = [&](const u16* g, int ldsOff) {
    #pragma unroll
    for (int r = 0; r < 2; ++r)
      gload16(g + goff[r], smem + ldsOff + r * 8192 + w * 1024);
  };

  const u16* A0 = A  + (size_t)m0 * K;
  const u16* A1 = A  + (size_t)(m0 + 128) * K;
  const u16* B0 = Bt + (size_t)n0 * K;
  const u16* B1 = Bt + (size_t)(n0 + 128) * K;

  // swizzled per-lane fragment byte offset within a half
  const int aoff = (lrow * 64 + kq * 16) ^ ((lrow & 8) << 2);

  f32x4 acc[8][4] = {};
  bf16x8 a0[4][2], a1[4][2], b0[2][2], b1[2][2];

  // ---- prologue: stage t0 (A then B) -> buf0, t1 (A then B) -> buf1 ----
  // issue order defines vmcnt drain groups: [A(0),B(0)] then [A(1)] then [B(1)]
  stage_half(A0,       0);
  stage_half(A1,       16384);
  stage_half(B0,       32768);
  stage_half(B1,       49152);
  stage_half(A0 + 64,  65536);
  stage_half(A1 + 64,  65536 + 16384);
  stage_half(B0 + 64,  65536 + 32768);
  stage_half(B1 + 64,  65536 + 49152);
  asm volatile("s_waitcnt vmcnt(8)" ::: "memory");   // t0 resident (own stages)
  asm volatile("s_barrier" ::: "memory");            // -> all waves' t0 visible
  {
    const char* ab = smem + wm * 16384 + aoff;
    const char* bb = smem + 32768 + (wn >> 1) * 16384 + (wn & 1) * 8192 + aoff;
    #pragma unroll
    for (int i = 0; i < 4; ++i)
      #pragma unroll
      for (int kk = 0; kk < 2; ++kk)
        a0[i][kk] = *(const bf16x8*)(ab + (i*2 + kk) * 1024);
    #pragma unroll
    for (int j = 0; j < 2; ++j)
      #pragma unroll
      for (int kk = 0; kk < 2; ++kk)
        b0[j][kk] = *(const bf16x8*)(bb + (j*2 + kk) * 1024);
  }

  for (int t = 0; t < NT; ++t) {
    const int buf = t & 1;
    const char* ab  = smem + buf * 65536 + wm * 16384 + aoff;
    const char* bb  = smem + buf * 65536 + 32768 + (wn >> 1) * 16384 + (wn & 1) * 8192 + aoff;
    const char* abn = smem + (buf^1) * 65536 + wm * 16384 + aoff;
    const char* bbn = smem + (buf^1) * 65536 + 32768 + (wn >> 1) * 16384 + (wn & 1) * 8192 + aoff;

    // ===== p0: read a1[0..1] + b1 (8); MFMA q00(a0,b0) =====
    asm volatile("s_barrier" ::: "memory");
    #pragma unroll
    for (int i = 0; i < 2; ++i)
      #pragma unroll
      for (int kk = 0; kk < 2; ++kk)
        a1[i][kk] = *(const bf16x8*)(ab + ((4 + i)*2 + kk) * 1024);
    #pragma unroll
    for (int j = 0; j < 2; ++j)
      #pragma unroll
      for (int kk = 0; kk < 2; ++kk)
        b1[j][kk] = *(const bf16x8*)(bb + ((2 + j)*2 + kk) * 1024);
    __builtin_amdgcn_s_setprio(1);
    #pragma unroll
    for (int kk = 0; kk < 2; ++kk)
      #pragma unroll
      for (int i = 0; i < 4; ++i)
        #pragma unroll
        for (int j = 0; j < 2; ++j)
          acc[i][j] = __builtin_amdgcn_mfma_f32_16x16x32_bf16(a0[i][kk], b0[j][kk], acc[i][j], 0, 0, 0);
    __builtin_amdgcn_s_setprio(0);

    // ===== p1: read a1[2..3] (4); MFMA q01(a0,b1); lgkm drain; vmcnt(4) =====
    asm volatile("s_barrier" ::: "memory");
    #pragma unroll
    for (int i = 2; i < 4; ++i)
      #pragma unroll
      for (int kk = 0; kk < 2; ++kk)
        a1[i][kk] = *(const bf16x8*)(ab + ((4 + i)*2 + kk) * 1024);
    __builtin_amdgcn_s_setprio(1);
    #pragma unroll
    for (int kk = 0; kk < 2; ++kk)
      #pragma unroll
      for (int i = 0; i < 4; ++i)
        #pragma unroll
        for (int j = 0; j < 2; ++j)
          acc[i][2 + j] = __builtin_amdgcn_mfma_f32_16x16x32_bf16(a0[i][kk], b1[j][kk], acc[i][2 + j], 0, 0, 0);
    __builtin_amdgcn_s_setprio(0);
    asm volatile("s_waitcnt lgkmcnt(0)" ::: "memory");   // buf fully read -> dead
    if (t + 1 < NT)
      asm volatile("s_waitcnt vmcnt(4)" ::: "memory");   // A-halves(t+1) resident

    // ===== p2: read a0'(t+1) (8); stage Ah0,Ah1(t+2); MFMA q10(a1,b0) =====
    asm volatile("s_barrier" ::: "memory");
    if (t + 1 < NT) {
      #pragma unroll
      for (int i = 0; i < 4; ++i)
        #pragma unroll
        for (int kk = 0; kk < 2; ++kk)
          a0[i][kk] = *(const bf16x8*)(abn + (i*2 + kk) * 1024);
    }
    if (t + 2 < NT) {
      stage_half(A0 + (t+2)*64, buf*65536);
      stage_half(A1 + (t+2)*64, buf*65536 + 16384);
    }
    __builtin_amdgcn_s_setprio(1);
    #pragma unroll
    for (int kk = 0; kk < 2; ++kk)
      #pragma unroll
      for (int i = 0; i < 4; ++i)
        #pragma unroll
        for (int j = 0; j < 2; ++j)
          acc[4 + i][j] = __builtin_amdgcn_mfma_f32_16x16x32_bf16(a1[i][kk], b0[j][kk], acc[4 + i][j], 0, 0, 0);
    __builtin_amdgcn_s_setprio(0);
    if (t + 1 < NT) {
      if (t + 2 < NT) asm volatile("s_waitcnt vmcnt(4)" ::: "memory");  // B(t+1) resident
      else            asm volatile("s_waitcnt vmcnt(0)" ::: "memory");
    }

    // ===== p3: read b0'(t+1) (4); stage Bh0,Bh1(t+2); MFMA q11(a1,b1) =====
    asm volatile("s_barrier" ::: "memory");
    if (t + 1 < NT) {
      #pragma unroll
      for (int j = 0; j < 2; ++j)
        #pragma unroll
        for (int kk = 0; kk < 2; ++kk)
          b0[j][kk] = *(const bf16x8*)(bbn + (j*2 + kk) * 1024);
    }
    if (t + 2 < NT) {
      stage_half(B0 + (t+2)*64, buf*65536 + 32768);
      stage_half(B1 + (t+2)*64, buf*65536 + 49152);
    }
    __builtin_amdgcn_s_setprio(1);
    #pragma unroll
    for (int kk = 0; kk < 2; ++kk)
      #pragma unroll
      for (int i = 0; i < 4; ++i)
        #pragma unroll
        for (int j = 0; j < 2; ++j)
          acc[4 + i][2 + j] = __builtin_amdgcn_mfma_f32_16x16x32_bf16(a1[i][kk], b1[j][kk], acc[4 + i][2 + j], 0, 0, 0);
    __builtin_amdgcn_s_setprio(0);
  }

  // ---- epilogue ----
  #pragma unroll
  for (int i = 0; i < 8; ++i)
    #pragma unroll
    for (int j = 0; j < 4; ++j)
      #pragma unroll
      for (int r = 0; r < 4; ++r) {
        int row = m0 + wm*128 + i*16 + kq*4 + r;
        int col = n0 + wn*64 + j*16 + lrow;
        size_t idx = (size_t)row * N + col;
        float v = acc[i][j][r];
        if (EPI == 0) {
          Cb[idx] = f2bf(v);
        } else if (EPI == 3) {
          Cf[idx] = v;
        } else {
          float g = 0.5f * v * (1.0f + erff(v * 0.70710678118654752f));
          Cb[idx] = f2bf(g);
        }
      }
}

// ---- prep: split heads + per-head exp_map ----
__global__ void prep_qk(const u16* __restrict__ in, const float* __restrict__ headK,
                        u16* __restrict__ Lout, float* __restrict__ l0,
                        int instride, int off) {
  int gid = blockIdx.x * 4 + (threadIdx.x >> 6);
  int lane = threadIdx.x & 63;
  int b = gid >> 15;
  int rem = gid & 32767;
  int h = rem >> 11;
  int s = rem & 2047;
  const u16* src = in + ((size_t)(b * SEQ + s)) * instride + off + h * DHEAD + lane * 2;
  float v0 = bf2f(src[0]), v1 = bf2f(src[1]);
  float nn = v0*v0 + v1*v1;
  #pragma unroll
  for (int m = 1; m < 64; m <<= 1) nn += __shfl_xor(nn, m, 64);
  float Kh = headK[h];
  float sk = sqrtf(-Kh);
  float a = sk * sqrtf(nn);
  float f = (a < 1e-6f) ? (1.0f + a*a*(1.0f/6.0f)) : (sinhf(a) / a);
  u16* dst = Lout + (size_t)gid * DHEAD + lane * 2;
  dst[0] = f2bf(f * v0);
  dst[1] = f2bf(f * v1);
  if (lane == 0) l0[gid] = sqrtf(-1.0f/Kh + f*f*nn);
}

// ---- vtrans ----
__global__ void vtrans(const u16* __restrict__ vb, u16* __restrict__ VT,
                       int instride, int off) {
  __shared__ u16 tile[32][33];
  int bh = blockIdx.x;
  int b = bh >> 4, h = bh & 15;
  int s0 = blockIdx.y * 32, d0 = blockIdx.z * 32;
  int tx = threadIdx.x, ty = threadIdx.y;
  #pragma unroll
  for (int i = 0; i < 4; ++i)
    tile[ty + 8*i][tx] = vb[((size_t)(b*SEQ + s0 + ty + 8*i)) * instride + off + h*DHEAD + d0 + tx];
  __syncthreads();
  #pragma unroll
  for (int i = 0; i < 4; ++i)
    VT[((size_t)bh*DHEAD + d0 + ty + 8*i) * SEQ + s0 + tx] = tile[tx][ty + 8*i];
}

// -------- flash attention v4: LDS double-buffer via gload16, swizzled, raw barriers --------
__global__ __launch_bounds__(256, 2) void attn_kernel(
    const u16* __restrict__ Ql, const u16* __restrict__ Kl,
    const u16* __restrict__ VT, const float* __restrict__ ql0,
    const float* __restrict__ kl0, const float* __restrict__ headK,
    u16* __restrict__ out) {
  __shared__ u16 klds[2][32 * 128];
  __shared__ u16 vlds[2][128 * 32];
  __shared__ u16 plds[4][32 * 36];
  const int tid = threadIdx.x, w = tid >> 6, lane = tid & 63;
  const int lrow = lane & 15, kq = lane >> 4;
  const int id = blockIdx.x;
  const int bh = id & 31;
  const int qb = 15 - (id >> 5);
  const int q0 = qb * 128 + w * 32;
  const int b = bh >> 4, h = bh & 15;
  const float Kh = headK[h];
  const float LOG2E = 1.44269504088896f;
  const float isd = 0.088388347648318447f;
  const float sc_mul = 2.0f * isd * LOG2E;
  const float sc_add = (-2.0f / Kh) * isd * LOG2E;

  const u16* kbase  = Kl + (size_t)bh * SEQ * DHEAD;
  const u16* vtbase = VT + (size_t)bh * DHEAD * SEQ;
  const float* kl0b = kl0 + (size_t)bh * SEQ;
  u16* pw = &plds[w][0];

  bf16x8 aq[2][4];
  const u16* qbase = Ql + ((size_t)bh * SEQ + q0) * DHEAD;
  #pragma unroll
  for (int m = 0; m < 2; ++m)
    #pragma unroll
    for (int dc = 0; dc < 4; ++dc)
      aq[m][dc] = *(const bf16x8*)&qbase[(size_t)(m*16 + lrow) * DHEAD + dc*32 + kq*8];
  float q0r[2][4];
  #pragma unroll
  for (int m = 0; m < 2; ++m)
    #pragma unroll
    for (int r = 0; r < 4; ++r)
      q0r[m][r] = ql0[(size_t)bh * SEQ + q0 + m*16 + kq*4 + r];

  auto stage = [&](int k0, int buf) {
    #pragma unroll
    for (int i = 0; i < 2; ++i) {
      int rl = w*8 + i*4 + (lane >> 4);
      int c = (lane & 15) ^ (rl & 15);
      gload16(kbase + ((size_t)(k0 + rl)) * DHEAD + c * 8,
              &klds[buf][(w*8 + i*4) * 128]);
    }
    #pragma unroll
    for (int i = 0; i < 2; ++i) {
      int rl = w*32 + i*16 + (lane >> 2);
      int c = (lane & 3) ^ ((rl >> 1) & 3);
      gload16(vtbase + (size_t)rl * SEQ + k0 + c * 8,
              &vlds[buf][(w*32 + i*16) * 32]);
    }
  };

  float lacc[2][4] = {};
  f32x4 o[2][8] = {};
  const int niter = qb * 4 + 4;

  stage(0, 0);
  for (int i = 0; i < niter; ++i) {
    const int k0 = i * 32, buf = i & 1;
    float kc0 = kl0b[k0 + lrow];
    float kc1 = kl0b[k0 + 16 + lrow];
    if (i + 1 < niter) {
      stage(k0 + 32, buf ^ 1);
      asm volatile("s_waitcnt vmcnt(4)" ::: "memory");
    } else {
      asm volatile("s_waitcnt vmcnt(0)" ::: "memory");
    }
    asm volatile("s_barrier" ::: "memory");

    f32x4 sc[2][2] = {};
    __builtin_amdgcn_s_setprio(1);
    #pragma unroll
    for (int dc = 0; dc < 4; ++dc) {
      int c = dc*4 + kq;
      bf16x8 bk0 = *(const bf16x8*)&klds[buf][lrow*128        + (c ^ (lrow & 15)) * 8];
      bf16x8 bk1 = *(const bf16x8*)&klds[buf][(16 + lrow)*128 + (c ^ ((16 + lrow) & 15)) * 8];
      #pragma unroll
      for (int m = 0; m < 2; ++m) {
        sc[m][0] = __builtin_amdgcn_mfma_f32_16x16x32_bf16(aq[m][dc], bk0, sc[m][0], 0, 0, 0);
        sc[m][1] = __builtin_amdgcn_mfma_f32_16x16x32_bf16(aq[m][dc], bk1, sc[m][1], 0, 0, 0);
      }
    }
    __builtin_amdgcn_s_setprio(0);
    #pragma unroll
    for (int m = 0; m < 2; ++m)
      #pragma unroll
      for (int r = 0; r < 4; ++r) {
        int qg = q0 + m*16 + kq*4 + r;
        float p0 = exp2f((sc[m][0][r] - q0r[m][r] * kc0) * sc_mul + sc_add);
        float p1 = exp2f((sc[m][1][r] - q0r[m][r] * kc1) * sc_mul + sc_add);
        p0 = (k0 + lrow      <= qg) ? p0 : 0.f;
        p1 = (k0 + 16 + lrow <= qg) ? p1 : 0.f;
        lacc[m][r] += p0 + p1;
        pw[(m*16 + kq*4 + r) * 36 + lrow]      = f2bf(p0);
        pw[(m*16 + kq*4 + r) * 36 + 16 + lrow] = f2bf(p1);
      }
    bf16x8 ap0 = *(const bf16x8*)&pw[(size_t)lrow * 36 + kq*8];
    bf16x8 ap1 = *(const bf16x8*)&pw[(size_t)(16 + lrow) * 36 + kq*8];
    int vc = (kq ^ ((lrow >> 1) & 3)) * 8;
    __builtin_amdgcn_s_setprio(1);
    #pragma unroll
    for (int n = 0; n < 8; ++n) {
      bf16x8 bv = *(const bf16x8*)&vlds[buf][(n*16 + lrow) * 32 + vc];
      o[0][n] = __builtin_amdgcn_mfma_f32_16x16x32_bf16(ap0, bv, o[0][n], 0, 0, 0);
      o[1][n] = __builtin_amdgcn_mfma_f32_16x16x32_bf16(ap1, bv, o[1][n], 0, 0, 0);
    }
    __builtin_amdgcn_s_setprio(0);
    asm volatile("s_barrier" ::: "memory");
  }

  float rcl[2][4];
  #pragma unroll
  for (int m = 0; m < 2; ++m)
    #pragma unroll
    for (int r = 0; r < 4; ++r) {
      float s = lacc[m][r];
      #pragma unroll
      for (int mm = 1; mm < 16; mm <<= 1) s += __shfl_xor(s, mm, 16);
      rcl[m][r] = 1.0f / s;
    }
  #pragma unroll
  for (int m = 0; m < 2; ++m)
    #pragma unroll
    for (int n = 0; n < 8; ++n)
      #pragma unroll
      for (int r = 0; r < 4; ++r) {
        int qg = q0 + m*16 + kq*4 + r;
        out[((size_t)b * SEQ + qg) * DMODEL + h * DHEAD + n*16 + lrow] =
            f2bf(o[m][n][r] * rcl[m][r]);
      }
}

extern "C" void kernel_launch(void* const* d_in, const int* in_sizes, int n_in,
                              void* d_out, int out_size, void* d_ws, size_t ws_size,
                              hipStream_t stream) {
  const float* x      = (const float*)d_in[0];
  const float* scale1 = (const float*)d_in[2];
  const float* scale2 = (const float*)d_in[3];
  const float* Wq     = (const float*)d_in[4];
  const float* Wk     = (const float*)d_in[5];
  const float* Wv     = (const float*)d_in[6];
  const float* Wo     = (const float*)d_in[7];
  const float* headK  = (const float*)d_in[8];
  const float* W1     = (const float*)d_in[9];
  const float* W2     = (const float*)d_in[10];
  float* out = (float*)d_out;

  char* p = (char*)d_ws;
  size_t off = 0;
  auto take = [&](size_t bytes) -> char* {
    char* r = p + off;
    off += (bytes + 255) & ~(size_t)255;
    return r;
  };
  u16* WqT = (u16*)take((size_t)DMODEL*DMODEL*2);   // WqT/WkT/WvT/WoT contiguous 32MB
  u16* WkT = (u16*)take((size_t)DMODEL*DMODEL*2);
  u16* WvT = (u16*)take((size_t)DMODEL*DMODEL*2);
  u16* WoT = (u16*)take((size_t)DMODEL*DMODEL*2);
  u16* W1T = (u16*)take((size_t)DMODEL*DFFN*2);
  u16* W2T = (u16*)take((size_t)DMODEL*DFFN*2);
  float* vres = (float*)take((size_t)MROWS*DMODEL*4);   // v1 -> u2 (in place)
  u16* tbuf = (u16*)take((size_t)MROWS*DMODEL*2);       // t1, attn_out, t2
  u16* qkvb = (u16*)take((size_t)MROWS*3*DMODEL*2);     // fused QKV out (4096 x 6144)
  u16* Qlb  = (u16*)take((size_t)MROWS*DMODEL*2);       // qkvb+Qlb = 64MB contiguous
  u16* Klb  = (u16*)take((size_t)MROWS*DMODEL*2);
  u16* VTb  = (u16*)take((size_t)MROWS*DMODEL*2);
  float* q0b = (float*)take((size_t)NB*NHEAD*SEQ*4);
  float* k0b = (float*)take((size_t)NB*NHEAD*SEQ*4);
  u16* hbuf = qkvb;     // reuse qkvb..Qlb contiguous 64MB = MROWS*DFFN bf16
  u16* attnout = tbuf;  // t1 consumed by QKV gemm before attention writes here

  // K-split partial buffers (scavenged):
  float* PoA = (float*)qkvb;       // Wo partials (region free until rms_mid3)
  float* PfA = (float*)WqT;        // W2 partials: WqT..WoT + W1T contiguous 64MB

  dim3 tb(32, 8);
  transpose_w<<<dim3(DMODEL/32, DMODEL/32), tb, 0, stream>>>(Wq, WqT, DMODEL, DMODEL);
  transpose_w<<<dim3(DMODEL/32, DMODEL/32), tb, 0, stream>>>(Wk, WkT, DMODEL, DMODEL);
  transpose_w<<<dim3(DMODEL/32, DMODEL/32), tb, 0, stream>>>(Wv, WvT, DMODEL, DMODEL);
  transpose_w<<<dim3(DMODEL/32, DMODEL/32), tb, 0, stream>>>(Wo, WoT, DMODEL, DMODEL);
  transpose_w<<<dim3(DFFN/32,   DMODEL/32), tb, 0, stream>>>(W1, W1T, DMODEL, DFFN);
  transpose_w<<<dim3(DMODEL/32, DFFN/32),   tb, 0, stream>>>(W2, W2T, DFFN, DMODEL);

  ln_first<<<MROWS, 256, 0, stream>>>(x, scale1, vres, tbuf);

  // fused QKV: M=4096, N=6144, K=2048 -> 384 blocks, no split
  gemm256<0><<<dim3((3*DMODEL/256)*(MROWS/256), 1), 512, 0, stream>>>(
      tbuf, WqT, qkvb, nullptr, MROWS, 3*DMODEL, DMODEL, DMODEL);

  prep_qk<<<NB*NHEAD*SEQ/4, 256, 0, stream>>>(qkvb, headK, Qlb, q0b, 3*DMODEL, 0);
  prep_qk<<<NB*NHEAD*SEQ/4, 256, 0, stream>>>(qkvb, headK, Klb, k0b, 3*DMODEL, DMODEL);
  vtrans<<<dim3(NB*NHEAD, SEQ/32, DHEAD/32), tb, 0, stream>>>(qkvb, VTb, 3*DMODEL, 2*DMODEL);

  attn_kernel<<<dim3(512), 256, 0, stream>>>(Qlb, Klb, VTb, q0b, k0b, headK, attnout);

  // Wo: M=4096, N=2048, K=2048, K-split 2 -> (128,2) blocks, fp32 partials
  gemm256<3><<<dim3((DMODEL/256)*(MROWS/256), 2), 512, 0, stream>>>(
      attnout, WoT, nullptr, PoA, MROWS, DMODEL, DMODEL, DMODEL/2);

  // u2 = v1 + PoA + PoB (in place) ; t2 = scale2 * u2 / rms
  rms_mid3<<<MROWS, 256, 0, stream>>>(vres, PoA, PoA + (size_t)MROWS*DMODEL, scale2, tbuf);

  // W1 + gelu: M=4096, N=8192, K=2048 -> 512 blocks, no split
  gemm256<2><<<dim3((DFFN/256)*(MROWS/256), 1), 512, 0, stream>>>(
      tbuf, W1T, hbuf, nullptr, MROWS, DFFN, DMODEL, DMODEL);

  // W2: M=4096, N=2048, K=8192, K-split 2 -> (128,2) blocks, fp32 partials
  // into WqT..W1T (contiguous 64MB, both regions dead here)
  gemm256<3><<<dim3((DMODEL/256)*(MROWS/256), 2), 512, 0, stream>>>(
      hbuf, W2T, nullptr, PfA, MROWS, DMODEL, DFFN, DFFN/2);

  final_exp3<<<MROWS, 256, 0, stream>>>(vres, PfA, PfA + (size_t)MROWS*DMODEL, out);

  (void)in_sizes; (void)n_in; (void)out_size; (void)ws_size;
}